// Round 7
// baseline (4640.536 us; speedup 1.0000x reference)
//
#include <hip/hip_runtime.h>

#define LDF 68
#define EPSF 1e-8f
#define MFMA(A,B,C) __builtin_amdgcn_mfma_f32_16x16x32_bf16((A),(B),(C),0,0,0)

typedef __attribute__((ext_vector_type(8))) short bf16x8;
typedef __attribute__((ext_vector_type(4))) float f32x4;

__device__ __forceinline__ float sigf(float x){ return 1.0f/(1.0f + __expf(-x)); }

__device__ __forceinline__ unsigned short f2bf(float f){
  unsigned u = __float_as_uint(f);
  u += 0x7FFFu + ((u >> 16) & 1u);
  return (unsigned short)(u >> 16);
}
__device__ __forceinline__ float bf2f(unsigned short s){
  return __uint_as_float((unsigned)s << 16);
}

// packed-activation element index (u16 units) within one plane
__device__ __forceinline__ size_t pk(int b, int col, int KB){
  return ((((size_t)((b>>4)*KB + (col>>5)))*64) + (size_t)((b&15) + (((col>>3)&3)<<4)))*8 + (col&7);
}

__device__ __forceinline__ void gload_lds16(const void* g, void* l){
  __builtin_amdgcn_global_load_lds(
      (const __attribute__((address_space(1))) void*)g,
      (__attribute__((address_space(3))) void*)l, 16, 0, 0);
}

// ---------------- init kernels ----------------
__global__ void reorder_gates(const float* __restrict__ src, float* __restrict__ dst,
                              int H, int K, int total){
  int idx = blockIdx.x*256 + threadIdx.x;
  if (idx >= total) return;
  int row = idx / K;
  int col = idx - row*K;
  int j = row >> 2, g = row & 3;
  dst[idx] = src[(size_t)(g*H + j)*K + col];
}

__global__ void pack_w_mfma(const float* __restrict__ Wih, const float* __restrict__ Whh,
                            int K_ih, int K_tot,
                            unsigned short* __restrict__ dhi, unsigned short* __restrict__ dlo,
                            int total8){
  int idx = blockIdx.x*256 + threadIdx.x;
  if (idx >= total8) return;
  int lane = idx & 63;
  int rest = idx >> 6;
  int KB = K_tot >> 5;
  int kb = rest % KB;
  int fm = rest / KB;
  int rr = fm*16 + (lane & 15);
  int orow = (rr & 3)*512 + (rr >> 2);     // gate reorder fused
  int k0 = kb*32 + (lane >> 4)*8;
  union { unsigned short s[8]; uint4 u; } vh, vl;
  #pragma unroll
  for (int i = 0; i < 8; i++){
    int k = k0 + i;
    float f = (k < K_ih) ? Wih[(size_t)orow*K_ih + k]
                         : Whh[(size_t)orow*512 + (k - K_ih)];
    unsigned short hi = f2bf(f);
    vh.s[i] = hi;
    vl.s[i] = f2bf(f - bf2f(hi));
  }
  *(uint4*)(dhi + (size_t)idx*8) = vh.u;
  *(uint4*)(dlo + (size_t)idx*8) = vl.u;
}

__global__ void pack_wz_mfma(const float* __restrict__ muW, const float* __restrict__ sigW,
                             unsigned short* __restrict__ dhi, unsigned short* __restrict__ dlo){
  int idx = blockIdx.x*256 + threadIdx.x;
  if (idx >= 16384) return;
  int lane = idx & 63, rest = idx >> 6;
  int kb = rest & 15, fmf = rest >> 4;
  int row = fmf*16 + (lane & 15);
  const float* src = (row < 128) ? (muW + (size_t)row*512) : (sigW + (size_t)(row-128)*512);
  int k0 = kb*32 + (lane >> 4)*8;
  union { unsigned short s[8]; uint4 u; } vh, vl;
  #pragma unroll
  for (int i = 0; i < 8; i++){
    float f = src[k0 + i];
    unsigned short hi = f2bf(f);
    vh.s[i] = hi;
    vl.s[i] = f2bf(f - bf2f(hi));
  }
  *(uint4*)(dhi + (size_t)idx*8) = vh.u;
  *(uint4*)(dlo + (size_t)idx*8) = vl.u;
}

__global__ void transpose_ww(const float* __restrict__ W, float* __restrict__ dst){
  int idx = blockIdx.x*256 + threadIdx.x;
  if (idx >= 512*64) return;
  int k = idx >> 6, n = idx & 63;
  dst[idx] = W[n*512 + k];
}

__global__ void zero_f(float* p, int n){
  int idx = blockIdx.x*256 + threadIdx.x;
  if (idx < n) p[idx] = 0.f;
}

// ---------------- shared-memory layout (union across phases) ----------------
struct WgS {
  float hs[512];
  float Fx[8*LDF], Fy[8*LDF], pl[8];
  float cs[64*LDF];
  float img_s[64*LDF];
  float P[2][8*LDF];
  float ps[4][64], w_s[64];
  float tmp[64*8];
};
union SMem {
  unsigned char glds[3][8192];
  WgS wg[2];
};

// ---------------- grid barrier (manual, device-scope, monotonic) ----------------
__device__ __forceinline__ void grid_sync(unsigned int* bar, unsigned int target){
  __syncthreads();
  if (threadIdx.x == 0){
    __threadfence();
    __hip_atomic_fetch_add(bar, 1u, __ATOMIC_ACQ_REL, __HIP_MEMORY_SCOPE_AGENT);
    while (__hip_atomic_load(bar, __ATOMIC_ACQUIRE, __HIP_MEMORY_SCOPE_AGENT) < target)
      __builtin_amdgcn_s_sleep(2);
  }
  __syncthreads();
  __threadfence();
}

// ---------------- attention window (one 256-thread half) ----------------
__device__ void attn_window2(WgS& S, int t,
                             const float* __restrict__ attn_W,
                             const float* __restrict__ attn_b)
{
  int lane = t & 63, wid = t >> 6;
  for (int q = wid; q < 5; q += 4){
    float s = 0.f;
    for (int k = lane; k < 512; k += 64) s += S.hs[k]*attn_W[q*512 + k];
    for (int m = 32; m; m >>= 1) s += __shfl_xor(s, m);
    if (lane == 0) S.pl[q] = s + attn_b[q];
  }
  __syncthreads();
  float gx    = 32.5f*(S.pl[0] + 1.f);
  float gy    = 32.5f*(S.pl[1] + 1.f);
  float s2    = __expf(S.pl[2]);
  float delta = 9.f*__expf(S.pl[3]);
  float inv2  = 1.f/(2.f*s2);
  int n = t >> 5, a = t & 31;
  float mux = gx + ((float)n - 4.5f)*delta;
  float muy = gy + ((float)n - 4.5f)*delta;
  float dx0 = (float)a      - mux, dx1 = (float)(a+32) - mux;
  float dy0 = (float)a      - muy, dy1 = (float)(a+32) - muy;
  float e0 = __expf(-dx0*dx0*inv2), e1 = __expf(-dx1*dx1*inv2);
  float f0 = __expf(-dy0*dy0*inv2), f1 = __expf(-dy1*dy1*inv2);
  float sx = e0 + e1, sy = f0 + f1;
  for (int m = 16; m; m >>= 1){ sx += __shfl_xor(sx, m); sy += __shfl_xor(sy, m); }
  float rx = 1.f/(sx + EPSF), ry = 1.f/(sy + EPSF);
  S.Fx[n*LDF + a]      = e0*rx;  S.Fx[n*LDF + a + 32] = e1*rx;
  S.Fy[n*LDF + a]      = f0*ry;  S.Fy[n*LDF + a + 32] = f1*ry;
  __syncthreads();
}

// ---------------- fused write(t) + glimpse(t+1), one batch per 256-thread half ----------------
__device__ void wg_phase(WgS& S, int t, int b,
    const float* __restrict__ h_dec,
    const float* __restrict__ WwT, const float* __restrict__ write_b,
    const float* __restrict__ attn_W, const float* __restrict__ attn_b,
    const float* __restrict__ canvas_prev, float* __restrict__ canvas_out,
    const float* __restrict__ x,
    unsigned short* __restrict__ rout, int planeE)
{
  for (int i = t; i < 128; i += 256)
    ((float4*)S.hs)[i] = ((const float4*)(h_dec + (size_t)b*512))[i];
  if (rout){
    const float4* x4 = (const float4*)(x + (size_t)b*4096);
    for (int i = t; i < 1024; i += 256){
      int row = i >> 4, cb = (i & 15)*4;
      *(float4*)&S.img_s[row*LDF + cb] = x4[i];
    }
  }
  __syncthreads();
  attn_window2(S, t, attn_W, attn_b);
  float gamma = __expf(S.pl[4]);

  if (canvas_out){
    {
      int j = t & 63, part = t >> 6;
      float s = 0.f;
      int kb = part*128;
      for (int k = 0; k < 128; k++) s += S.hs[kb + k] * WwT[(kb + k)*64 + j];
      S.ps[part][j] = s;
    }
    __syncthreads();
    if (t < 64)
      S.w_s[t] = write_b[t] + S.ps[0][t] + S.ps[1][t] + S.ps[2][t] + S.ps[3][t];
    __syncthreads();
    float inv_g = __expf(-S.pl[4]);
    #pragma unroll
    for (int e = 0; e < 2; e++){
      int gi = e*256 + t;
      int m = gi & 7, hh = gi >> 3;
      float s = 0.f;
      #pragma unroll
      for (int nn = 0; nn < 8; nn++) s += S.Fy[nn*LDF + hh] * S.w_s[nn*8 + m];
      S.tmp[hh*8 + m] = s;
    }
    __syncthreads();
    for (int e = 0; e < 16; e++){
      int idx = e*256 + t;
      int hh = idx >> 6, a = idx & 63;
      float s = 0.f;
      #pragma unroll
      for (int m = 0; m < 8; m++) s += S.tmp[hh*8 + m] * S.Fx[m*LDF + a];
      float prev = canvas_prev ? canvas_prev[(size_t)b*4096 + idx] : 0.f;
      float cv = prev + s*inv_g;
      canvas_out[(size_t)b*4096 + idx] = cv;
      S.cs[hh*LDF + a] = cv;
    }
  } else {
    for (int e = 0; e < 16; e++){
      int idx = e*256 + t;
      S.cs[(idx >> 6)*LDF + (idx & 63)] = 0.f;
    }
  }

  if (rout){
    __syncthreads();
    for (int e = 0; e < 16; e++){
      int idx = e*256 + t;
      int hh = idx >> 6, a = idx & 63;
      S.cs[hh*LDF + a] = sigf(S.cs[hh*LDF + a]);
    }
    __syncthreads();
    #pragma unroll
    for (int e = 0; e < 4; e++){
      int gi = e*256 + t;
      int d = gi >> 9, rem = gi & 511;
      int m = rem & 7, hh = rem >> 3;
      const float* Ssrc = d ? S.cs : S.img_s;
      float s = 0.f;
      #pragma unroll
      for (int w4 = 0; w4 < 64; w4 += 4){
        float4 iv = *(const float4*)&Ssrc[hh*LDF + w4];
        float4 fv = *(const float4*)&S.Fx[m*LDF + w4];
        s += iv.x*fv.x + iv.y*fv.y + iv.z*fv.z + iv.w*fv.w;
      }
      S.P[d][m*LDF + hh] = s;
    }
    __syncthreads();
    if (t < 128){
      int d = t >> 6, l = t & 63;
      int n = l >> 3, m = l & 7;
      float s = 0.f;
      #pragma unroll
      for (int h4 = 0; h4 < 64; h4 += 4){
        float4 fv = *(const float4*)&S.Fy[n*LDF + h4];
        float4 pv = *(const float4*)&S.P[d][m*LDF + h4];
        s += fv.x*pv.x + fv.y*pv.y + fv.z*pv.z + fv.w*pv.w;
      }
      S.tmp[d*64 + l] = s;
    }
    __syncthreads();
    if (t < 64){
      float g1 = S.tmp[t]*gamma;
      float g2 = (S.tmp[t] - S.tmp[64 + t])*gamma;
      unsigned short h1 = f2bf(g1), l1 = f2bf(g1 - bf2f(h1));
      unsigned short h2 = f2bf(g2), l2 = f2bf(g2 - bf2f(h2));
      size_t o1 = pk(b, t, 36);
      size_t o2 = pk(b, 64 + t, 36);
      rout[o1] = h1; rout[o1 + planeE] = l1;
      rout[o2] = h2; rout[o2 + planeE] = l2;
    }
  }
}

// ---------------- MFMA GEMM phase (split hi/lo, counted-vmcnt 3-deep pipeline) ----------------
template<int KB>
__device__ void gemm_phase(unsigned char (&lds)[3][8192],
    const bf16x8* __restrict__ Wh, const bf16x8* __restrict__ Wl,
    const unsigned short* __restrict__ act, int actPlane,
    const float4* __restrict__ bias4, const float* __restrict__ c_in,
    float* __restrict__ h_f32, float* __restrict__ c_out,
    unsigned short* __restrict__ out0, int KB0, int off0, int plane0,
    unsigned short* __restrict__ out1, int KB1, int off1, int plane1)
{
  const int tid = threadIdx.x, lane = tid & 63, w = tid >> 6;
  const int mt = blockIdx.x & 31, nt = blockIdx.x >> 5;
  const int fm = w & 3, fn0 = (w >> 2) << 1;

  const bf16x8* whp = Wh + ((size_t)(mt*4+fm)*KB)*64 + lane;
  const bf16x8* wlp = Wl + ((size_t)(mt*4+fm)*KB)*64 + lane;

  const char* ast = (const char*)act + (size_t)(w & 1)*((size_t)actPlane*2)
                  + ((size_t)(nt*4 + (w >> 1))*KB)*1024 + (size_t)lane*16;

  const int j0 = (mt*4+fm)*4 + (lane >> 4);
  float4 bb = bias4[j0];
  f32x4 acc0 = {bb.x, bb.y, bb.z, bb.w};
  f32x4 acc1 = acc0;

  asm volatile("s_waitcnt vmcnt(0)" ::: "memory");
  gload_lds16(ast, (char*)&lds[0][w*1024]);
  bf16x8 whA = whp[0], wlA = wlp[0];
  __builtin_amdgcn_sched_barrier(0);
  asm volatile("" ::: "memory");
  gload_lds16(ast + 1024, (char*)&lds[1][w*1024]);
  bf16x8 whB = whp[64], wlB = wlp[64];
  __builtin_amdgcn_sched_barrier(0);
  asm volatile("" ::: "memory");

  const size_t rdoff = (size_t)fn0*2048 + (size_t)lane*16;

  #pragma unroll
  for (int kb = 0; kb < KB; kb++){
    if (kb + 1 < KB) asm volatile("s_waitcnt vmcnt(3)" ::: "memory");
    else             asm volatile("s_waitcnt vmcnt(0)" ::: "memory");
    __builtin_amdgcn_s_barrier();
    asm volatile("" ::: "memory");
    __builtin_amdgcn_sched_barrier(0);
    bf16x8 whC = whA, wlC = wlA;
    if (kb + 2 < KB){
      gload_lds16(ast + (size_t)(kb+2)*1024, (char*)&lds[(kb+2)%3][w*1024]);
      whC = whp[(kb+2)*64]; wlC = wlp[(kb+2)*64];
    }
    const unsigned char* rb = &lds[kb%3][0] + rdoff;
    bf16x8 a0h = *(const bf16x8*)(rb);
    bf16x8 a0l = *(const bf16x8*)(rb + 1024);
    bf16x8 a1h = *(const bf16x8*)(rb + 2048);
    bf16x8 a1l = *(const bf16x8*)(rb + 3072);
    acc0 = MFMA(whA, a0h, acc0);
    acc1 = MFMA(whA, a1h, acc1);
    acc0 = MFMA(wlA, a0h, acc0);
    acc1 = MFMA(wlA, a1h, acc1);
    acc0 = MFMA(whA, a0l, acc0);
    acc1 = MFMA(whA, a1l, acc1);
    whA = whB; wlA = wlB; whB = whC; wlB = wlC;
  }

  const int bb0 = nt*64 + fn0*16 + (lane & 15);
  #pragma unroll
  for (int n = 0; n < 2; n++){
    f32x4 g = n ? acc1 : acc0;
    int b = bb0 + n*16;
    float ig = sigf(g[0]);
    float fg = sigf(g[1]);
    float gg = tanhf(g[2]);
    float og = sigf(g[3]);
    float c2 = fg * c_in[(size_t)b*512 + j0] + ig * gg;
    float h  = og * tanhf(c2);
    c_out[(size_t)b*512 + j0] = c2;
    if (h_f32) h_f32[(size_t)b*512 + j0] = h;
    unsigned short hh = f2bf(h);
    unsigned short hl = f2bf(h - bf2f(hh));
    size_t o0 = pk(b, off0 + j0, KB0);
    out0[o0] = hh; out0[o0 + plane0] = hl;
    if (out1){
      size_t o1 = pk(b, off1 + j0, KB1);
      out1[o1] = hh; out1[o1 + plane1] = hl;
    }
  }
}

// ---------------- z GEMM phase (wave 0 of each block) ----------------
__device__ void zgemm_phase(
    const bf16x8* __restrict__ Wzh, const bf16x8* __restrict__ Wzl,
    const unsigned short* __restrict__ az, int planeZ,
    const float* __restrict__ mu_b, const float* __restrict__ sig_b,
    const float* __restrict__ eps_t,
    unsigned short* __restrict__ actD, int planeD)
{
  const int fmb = blockIdx.x & 7, cg = blockIdx.x >> 3;
  const int lane = threadIdx.x;           // 0..63
  const bf16x8* wmh = Wzh + (size_t)(fmb    *16)*64 + lane;
  const bf16x8* wml = Wzl + (size_t)(fmb    *16)*64 + lane;
  const bf16x8* wsh = Wzh + (size_t)((fmb+8)*16)*64 + lane;
  const bf16x8* wsl = Wzl + (size_t)((fmb+8)*16)*64 + lane;
  const unsigned short* ab = az + (size_t)cg*8192 + (size_t)lane*8;

  const int r0 = fmb*16 + (lane >> 4)*4;
  float4 bm = *(const float4*)&mu_b[r0];
  float4 bs = *(const float4*)&sig_b[r0];
  f32x4 am = {bm.x, bm.y, bm.z, bm.w};
  f32x4 as = {bs.x, bs.y, bs.z, bs.w};

  #pragma unroll
  for (int kb = 0; kb < 16; kb++){
    bf16x8 ah = *(const bf16x8*)(ab + (size_t)kb*512);
    bf16x8 al = *(const bf16x8*)(ab + planeZ + (size_t)kb*512);
    bf16x8 h0 = wmh[kb*64], l0 = wml[kb*64];
    bf16x8 h1 = wsh[kb*64], l1 = wsl[kb*64];
    am = MFMA(h0, ah, am); am = MFMA(l0, ah, am); am = MFMA(h0, al, am);
    as = MFMA(h1, ah, as); as = MFMA(l1, ah, as); as = MFMA(h1, al, as);
  }

  const int b = cg*16 + (lane & 15);
  float4 ev = *(const float4*)&eps_t[(size_t)b*128 + r0];
  float e[4] = {ev.x, ev.y, ev.z, ev.w};
  union { unsigned short s[4]; uint2 u; } zh, zl;
  #pragma unroll
  for (int i = 0; i < 4; i++){
    float z = am[i] + e[i]*__expf(as[i]);
    unsigned short hi = f2bf(z);
    zh.s[i] = hi;
    zl.s[i] = f2bf(z - bf2f(hi));
  }
  size_t o = pk(b, r0, 20);
  *(uint2*)(actD + o) = zh.u;
  *(uint2*)(actD + planeD + o) = zl.u;
}

// ---------------- mega kernel: all 16 steps, manual grid barriers ----------------
struct MegaP {
  const unsigned short *WpEh, *WpEl, *WpDh, *WpDl, *Wzh, *Wzl;
  const float *bE, *bD, *WwT, *write_b, *attnW, *attn_b, *mu_b, *sig_b;
  const float *x, *eps;
  unsigned short *actE0, *actE1, *actD0, *actD1, *AZ;
  float *cE0, *cE1, *cD0, *cD1, *hD, *out;
  unsigned int *bar;
};

__global__ __launch_bounds__(512) void mega(MegaP P){
  __shared__ SMem sm;
  constexpr int PE = 512*1152, PD = 512*640, PZ = 512*512;
  unsigned short* actE[2] = {P.actE0, P.actE1};
  unsigned short* actD[2] = {P.actD0, P.actD1};
  float* cE[2] = {P.cE0, P.cE1};
  float* cD[2] = {P.cD0, P.cD1};
  const int tid = threadIdx.x;
  const int half = tid >> 8, t256 = tid & 255;
  const int b2 = blockIdx.x*2 + half;
  unsigned int sn = 0;

  // pre-loop glimpse (t=0): zero canvas, zero h_dec
  wg_phase(sm.wg[half], t256, b2, P.hD, P.WwT, P.write_b, P.attnW, P.attn_b,
           nullptr, nullptr, P.x, P.actE0, PE);
  grid_sync(P.bar, (++sn)*256);

  #pragma unroll 1
  for (int t = 0; t < 16; t++){
    const int cur = t & 1, nxt = cur ^ 1;

    gemm_phase<36>(sm.glds, (const bf16x8*)P.WpEh, (const bf16x8*)P.WpEl,
        actE[cur], PE, (const float4*)P.bE, cE[cur], nullptr, cE[nxt],
        P.AZ, 16, 0, PZ,
        actE[nxt], 36, 640, PE);
    grid_sync(P.bar, (++sn)*256);

    if (tid < 64)
      zgemm_phase((const bf16x8*)P.Wzh, (const bf16x8*)P.Wzl, P.AZ, PZ,
                  P.mu_b, P.sig_b, P.eps + (size_t)t*65536, actD[cur], PD);
    grid_sync(P.bar, (++sn)*256);

    gemm_phase<20>(sm.glds, (const bf16x8*)P.WpDh, (const bf16x8*)P.WpDl,
        actD[cur], PD, (const float4*)P.bD, cD[cur], P.hD, cD[nxt],
        actE[nxt], 36, 128, PE,
        actD[nxt], 20, 128, PD);
    grid_sync(P.bar, (++sn)*256);

    wg_phase(sm.wg[half], t256, b2, P.hD, P.WwT, P.write_b, P.attnW, P.attn_b,
             t ? (P.out + (size_t)(t-1)*2097152) : nullptr,
             P.out + (size_t)t*2097152, P.x,
             (t < 15) ? actE[nxt] : nullptr, PE);
    if (t < 15) grid_sync(P.bar, (++sn)*256);
  }
}

// ---------------- host launcher ----------------
extern "C" void kernel_launch(void* const* d_in, const int* in_sizes, int n_in,
                              void* d_out, int out_size, void* d_ws, size_t ws_size,
                              hipStream_t stream)
{
  (void)in_sizes; (void)n_in; (void)out_size; (void)ws_size;
  const float* x       = (const float*)d_in[0];
  const float* eps     = (const float*)d_in[1];
  const float* encWih  = (const float*)d_in[2];
  const float* encWhh  = (const float*)d_in[3];
  const float* enc_b   = (const float*)d_in[4];
  const float* muW     = (const float*)d_in[5];
  const float* mu_b    = (const float*)d_in[6];
  const float* sigW    = (const float*)d_in[7];
  const float* sig_b   = (const float*)d_in[8];
  const float* decWih  = (const float*)d_in[9];
  const float* decWhh  = (const float*)d_in[10];
  const float* dec_b   = (const float*)d_in[11];
  const float* writeW  = (const float*)d_in[12];
  const float* write_b = (const float*)d_in[13];
  const float* attnW   = (const float*)d_in[14];
  const float* attn_b  = (const float*)d_in[15];
  float* out = (float*)d_out;

  char* p = (char*)d_ws;
  auto alloc = [&](size_t bytes){ char* r = p; p += (bytes + 255) & ~(size_t)255; return r; };

  const int KE = 1152, KD = 640;
  const int PE = 512*KE, PD = 512*KD;
  const int T8E = 128*36*64, T8D = 128*20*64;

  unsigned short* WpEh = (unsigned short*)alloc((size_t)T8E*16);
  unsigned short* WpEl = (unsigned short*)alloc((size_t)T8E*16);
  unsigned short* WpDh = (unsigned short*)alloc((size_t)T8D*16);
  unsigned short* WpDl = (unsigned short*)alloc((size_t)T8D*16);
  unsigned short* Wzh  = (unsigned short*)alloc(16384*16);
  unsigned short* Wzl  = (unsigned short*)alloc(16384*16);
  float* bE  = (float*)alloc(2048*4);
  float* bD  = (float*)alloc(2048*4);
  float* WwT = (float*)alloc(512*64*4);
  // zero-init region: bar, actE0(hi+lo), actD0(hi+lo), hD, cE0, cD0
  char* z0 = p;
  unsigned int* bar = (unsigned int*)alloc(256);
  unsigned short* actE0 = (unsigned short*)alloc((size_t)2*PE*2);
  unsigned short* actD0 = (unsigned short*)alloc((size_t)2*PD*2);
  float* hD  = (float*)alloc(512*512*4);
  float* cE0 = (float*)alloc(512*512*4);
  float* cD0 = (float*)alloc(512*512*4);
  size_t zbytes = (size_t)(p - z0);
  unsigned short* actE1 = (unsigned short*)alloc((size_t)2*PE*2);
  unsigned short* actD1 = (unsigned short*)alloc((size_t)2*PD*2);
  unsigned short* AZ    = (unsigned short*)alloc((size_t)2*(512*512)*2);
  float* cE1 = (float*)alloc(512*512*4);
  float* cD1 = (float*)alloc(512*512*4);

  int tot;
  tot = T8E;   pack_w_mfma<<<(tot+255)/256,256,0,stream>>>(encWih, encWhh, 640, KE, WpEh, WpEl, tot);
  tot = T8D;   pack_w_mfma<<<(tot+255)/256,256,0,stream>>>(decWih, decWhh, 128, KD, WpDh, WpDl, tot);
  pack_wz_mfma<<<64,256,0,stream>>>(muW, sigW, Wzh, Wzl);
  tot = 2048;  reorder_gates<<<(tot+255)/256,256,0,stream>>>(enc_b, bE, 512, 1, tot);
  tot = 2048;  reorder_gates<<<(tot+255)/256,256,0,stream>>>(dec_b, bD, 512, 1, tot);
  tot = 512*64; transpose_ww<<<(tot+255)/256,256,0,stream>>>(writeW, WwT);
  tot = (int)(zbytes/4); zero_f<<<(tot+255)/256,256,0,stream>>>((float*)z0, tot);

  MegaP mp;
  mp.WpEh = WpEh; mp.WpEl = WpEl; mp.WpDh = WpDh; mp.WpDl = WpDl;
  mp.Wzh = Wzh; mp.Wzl = Wzl;
  mp.bE = bE; mp.bD = bD; mp.WwT = WwT; mp.write_b = write_b;
  mp.attnW = attnW; mp.attn_b = attn_b; mp.mu_b = mu_b; mp.sig_b = sig_b;
  mp.x = x; mp.eps = eps;
  mp.actE0 = actE0; mp.actE1 = actE1; mp.actD0 = actD0; mp.actD1 = actD1;
  mp.AZ = AZ;
  mp.cE0 = cE0; mp.cE1 = cE1; mp.cD0 = cD0; mp.cD1 = cD1;
  mp.hD = hD; mp.out = out; mp.bar = bar;

  mega<<<256,512,0,stream>>>(mp);
}

// Round 9
// 1701.095 us; speedup vs baseline: 2.7280x; 2.7280x over previous
//
#include <hip/hip_runtime.h>

#define LDF 68
#define EPSF 1e-8f
#define MFMA(A,B,C) __builtin_amdgcn_mfma_f32_16x16x32_bf16((A),(B),(C),0,0,0)

typedef __attribute__((ext_vector_type(8))) short bf16x8;
typedef __attribute__((ext_vector_type(4))) float f32x4;

__device__ __forceinline__ float sigf(float x){ return 1.0f/(1.0f + __expf(-x)); }

__device__ __forceinline__ unsigned short f2bf(float f){
  unsigned u = __float_as_uint(f);
  u += 0x7FFFu + ((u >> 16) & 1u);
  return (unsigned short)(u >> 16);
}
__device__ __forceinline__ float bf2f(unsigned short s){
  return __uint_as_float((unsigned)s << 16);
}

// packed-activation element index (u16 units) within one plane
__device__ __forceinline__ size_t pk(int b, int col, int KB){
  return ((((size_t)((b>>4)*KB + (col>>5)))*64) + (size_t)((b&15) + (((col>>3)&3)<<4)))*8 + (col&7);
}

// ---- explicit-asm loads (vmcnt counted manually by caller) ----
__device__ __forceinline__ uint4 ld_x4_sc(const void* p){   // device-coherent
  uint4 r;
  asm volatile("global_load_dwordx4 %0, %1, off sc0 sc1" : "=v"(r) : "v"(p));
  return r;
}
__device__ __forceinline__ uint4 ld_x4(const void* p){      // plain (L2-cached)
  uint4 r;
  asm volatile("global_load_dwordx4 %0, %1, off" : "=v"(r) : "v"(p));
  return r;
}
// ---- device-coherent stores ----
__device__ __forceinline__ void st_short_sc(void* p, unsigned short v){
  unsigned int vv = v;
  asm volatile("global_store_short %0, %1, off sc0 sc1" :: "v"(p), "v"(vv) : "memory");
}
__device__ __forceinline__ void st_dword_sc(void* p, float v){
  asm volatile("global_store_dword %0, %1, off sc0 sc1" :: "v"(p), "v"(v) : "memory");
}
__device__ __forceinline__ void st_dwordx2_sc(void* p, unsigned long long v){
  asm volatile("global_store_dwordx2 %0, %1, off sc0 sc1" :: "v"(p), "v"(v) : "memory");
}

// ---------------- init kernels ----------------
__global__ void reorder_gates(const float* __restrict__ src, float* __restrict__ dst,
                              int H, int K, int total){
  int idx = blockIdx.x*256 + threadIdx.x;
  if (idx >= total) return;
  int row = idx / K;
  int col = idx - row*K;
  int j = row >> 2, g = row & 3;
  dst[idx] = src[(size_t)(g*H + j)*K + col];
}

__global__ void pack_w_mfma(const float* __restrict__ Wih, const float* __restrict__ Whh,
                            int K_ih, int K_tot,
                            unsigned short* __restrict__ dhi, unsigned short* __restrict__ dlo,
                            int total8){
  int idx = blockIdx.x*256 + threadIdx.x;
  if (idx >= total8) return;
  int lane = idx & 63;
  int rest = idx >> 6;
  int KB = K_tot >> 5;
  int kb = rest % KB;
  int fm = rest / KB;
  int rr = fm*16 + (lane & 15);
  int orow = (rr & 3)*512 + (rr >> 2);     // gate reorder fused
  int k0 = kb*32 + (lane >> 4)*8;
  union { unsigned short s[8]; uint4 u; } vh, vl;
  #pragma unroll
  for (int i = 0; i < 8; i++){
    int k = k0 + i;
    float f = (k < K_ih) ? Wih[(size_t)orow*K_ih + k]
                         : Whh[(size_t)orow*512 + (k - K_ih)];
    unsigned short hi = f2bf(f);
    vh.s[i] = hi;
    vl.s[i] = f2bf(f - bf2f(hi));
  }
  *(uint4*)(dhi + (size_t)idx*8) = vh.u;
  *(uint4*)(dlo + (size_t)idx*8) = vl.u;
}

__global__ void pack_wz_mfma(const float* __restrict__ muW, const float* __restrict__ sigW,
                             unsigned short* __restrict__ dhi, unsigned short* __restrict__ dlo){
  int idx = blockIdx.x*256 + threadIdx.x;
  if (idx >= 16384) return;
  int lane = idx & 63, rest = idx >> 6;
  int kb = rest & 15, fmf = rest >> 4;
  int row = fmf*16 + (lane & 15);
  const float* src = (row < 128) ? (muW + (size_t)row*512) : (sigW + (size_t)(row-128)*512);
  int k0 = kb*32 + (lane >> 4)*8;
  union { unsigned short s[8]; uint4 u; } vh, vl;
  #pragma unroll
  for (int i = 0; i < 8; i++){
    float f = src[k0 + i];
    unsigned short hi = f2bf(f);
    vh.s[i] = hi;
    vl.s[i] = f2bf(f - bf2f(hi));
  }
  *(uint4*)(dhi + (size_t)idx*8) = vh.u;
  *(uint4*)(dlo + (size_t)idx*8) = vl.u;
}

__global__ void transpose_ww(const float* __restrict__ W, float* __restrict__ dst){
  int idx = blockIdx.x*256 + threadIdx.x;
  if (idx >= 512*64) return;
  int k = idx >> 6, n = idx & 63;
  dst[idx] = W[n*512 + k];
}

__global__ void zero_f(float* p, int n){
  int idx = blockIdx.x*256 + threadIdx.x;
  if (idx < n) p[idx] = 0.f;
}

// ---------------- shared-memory layout (union across phases) ----------------
struct WgS {
  float hs[512];
  float Fx[8*LDF], Fy[8*LDF], pl[8];
  float cs[64*LDF];
  float img_s[64*LDF];
  float P[2][8*LDF];
  float ps[4][64], w_s[64];
  float tmp[64*8];
};
union SMem {
  unsigned char glds[2][8192];
  float zred[8*64*8];
  WgS wg[2];
};

// ---------------- grid barrier: relaxed atomics, no cache maintenance ----------------
__device__ __forceinline__ void grid_sync(unsigned int* bar, unsigned int target){
  asm volatile("s_waitcnt vmcnt(0) lgkmcnt(0)" ::: "memory");
  __syncthreads();
  if (threadIdx.x == 0){
    __hip_atomic_fetch_add(bar, 1u, __ATOMIC_RELAXED, __HIP_MEMORY_SCOPE_AGENT);
    while (__hip_atomic_load(bar, __ATOMIC_RELAXED, __HIP_MEMORY_SCOPE_AGENT) < target)
      __builtin_amdgcn_s_sleep(4);
  }
  __syncthreads();
}

// ---------------- attention window (one 256-thread half) ----------------
__device__ void attn_window2(WgS& S, int t,
                             const float* __restrict__ attn_W,
                             const float* __restrict__ attn_b)
{
  int lane = t & 63, wid = t >> 6;
  for (int q = wid; q < 5; q += 4){
    float s = 0.f;
    for (int k = lane; k < 512; k += 64) s += S.hs[k]*attn_W[q*512 + k];
    for (int m = 32; m; m >>= 1) s += __shfl_xor(s, m);
    if (lane == 0) S.pl[q] = s + attn_b[q];
  }
  __syncthreads();
  float gx    = 32.5f*(S.pl[0] + 1.f);
  float gy    = 32.5f*(S.pl[1] + 1.f);
  float s2    = __expf(S.pl[2]);
  float delta = 9.f*__expf(S.pl[3]);
  float inv2  = 1.f/(2.f*s2);
  int n = t >> 5, a = t & 31;
  float mux = gx + ((float)n - 4.5f)*delta;
  float muy = gy + ((float)n - 4.5f)*delta;
  float dx0 = (float)a      - mux, dx1 = (float)(a+32) - mux;
  float dy0 = (float)a      - muy, dy1 = (float)(a+32) - muy;
  float e0 = __expf(-dx0*dx0*inv2), e1 = __expf(-dx1*dx1*inv2);
  float f0 = __expf(-dy0*dy0*inv2), f1 = __expf(-dy1*dy1*inv2);
  float sx = e0 + e1, sy = f0 + f1;
  for (int m = 16; m; m >>= 1){ sx += __shfl_xor(sx, m); sy += __shfl_xor(sy, m); }
  float rx = 1.f/(sx + EPSF), ry = 1.f/(sy + EPSF);
  S.Fx[n*LDF + a]      = e0*rx;  S.Fx[n*LDF + a + 32] = e1*rx;
  S.Fy[n*LDF + a]      = f0*ry;  S.Fy[n*LDF + a + 32] = f1*ry;
  __syncthreads();
}

// ---------------- fused write(t) + glimpse(t+1), one batch per 256-thread half ----------------
__device__ void wg_phase(WgS& S, int t, int b,
    const float* __restrict__ h_dec,          // cross-block -> sc asm staged
    const float* __restrict__ WwT, const float* __restrict__ write_b,
    const float* __restrict__ attn_W, const float* __restrict__ attn_b,
    const float* __restrict__ canvas_prev, float* __restrict__ canvas_out,
    const float* __restrict__ x,
    unsigned short* __restrict__ rout, int planeE)
{
  uint4 rh = {0,0,0,0};
  if (t < 128)
    rh = ld_x4_sc((const char*)(h_dec + (size_t)b*512) + (size_t)t*16);
  if (rout){
    const float4* x4 = (const float4*)(x + (size_t)b*4096);
    for (int i = t; i < 1024; i += 256){
      int row = i >> 4, cb = (i & 15)*4;
      *(float4*)&S.img_s[row*LDF + cb] = x4[i];
    }
  }
  asm volatile("s_waitcnt vmcnt(0)" ::: "memory");
  __builtin_amdgcn_sched_barrier(0);
  if (t < 128) *(uint4*)&S.hs[t*4] = rh;
  __syncthreads();
  attn_window2(S, t, attn_W, attn_b);
  float gamma = __expf(S.pl[4]);

  if (canvas_out){
    {
      int j = t & 63, part = t >> 6;
      float s = 0.f;
      int kb = part*128;
      for (int k = 0; k < 128; k++) s += S.hs[kb + k] * WwT[(kb + k)*64 + j];
      S.ps[part][j] = s;
    }
    __syncthreads();
    if (t < 64)
      S.w_s[t] = write_b[t] + S.ps[0][t] + S.ps[1][t] + S.ps[2][t] + S.ps[3][t];
    __syncthreads();
    float inv_g = __expf(-S.pl[4]);
    #pragma unroll
    for (int e = 0; e < 2; e++){
      int gi = e*256 + t;
      int m = gi & 7, hh = gi >> 3;
      float s = 0.f;
      #pragma unroll
      for (int nn = 0; nn < 8; nn++) s += S.Fy[nn*LDF + hh] * S.w_s[nn*8 + m];
      S.tmp[hh*8 + m] = s;
    }
    __syncthreads();
    for (int e = 0; e < 16; e++){
      int idx = e*256 + t;
      int hh = idx >> 6, a = idx & 63;
      float s = 0.f;
      #pragma unroll
      for (int m = 0; m < 8; m++) s += S.tmp[hh*8 + m] * S.Fx[m*LDF + a];
      float prev = canvas_prev ? canvas_prev[(size_t)b*4096 + idx] : 0.f;
      float cv = prev + s*inv_g;
      canvas_out[(size_t)b*4096 + idx] = cv;    // block-private across steps
      S.cs[hh*LDF + a] = cv;
    }
  } else {
    for (int e = 0; e < 16; e++){
      int idx = e*256 + t;
      S.cs[(idx >> 6)*LDF + (idx & 63)] = 0.f;
    }
  }

  if (rout){
    __syncthreads();
    for (int e = 0; e < 16; e++){
      int idx = e*256 + t;
      int hh = idx >> 6, a = idx & 63;
      S.cs[hh*LDF + a] = sigf(S.cs[hh*LDF + a]);
    }
    __syncthreads();
    #pragma unroll
    for (int e = 0; e < 4; e++){
      int gi = e*256 + t;
      int d = gi >> 9, rem = gi & 511;
      int m = rem & 7, hh = rem >> 3;
      const float* Ssrc = d ? S.cs : S.img_s;
      float s = 0.f;
      #pragma unroll
      for (int w4 = 0; w4 < 64; w4 += 4){
        float4 iv = *(const float4*)&Ssrc[hh*LDF + w4];
        float4 fv = *(const float4*)&S.Fx[m*LDF + w4];
        s += iv.x*fv.x + iv.y*fv.y + iv.z*fv.z + iv.w*fv.w;
      }
      S.P[d][m*LDF + hh] = s;
    }
    __syncthreads();
    if (t < 128){
      int d = t >> 6, l = t & 63;
      int n = l >> 3, m = l & 7;
      float s = 0.f;
      #pragma unroll
      for (int h4 = 0; h4 < 64; h4 += 4){
        float4 fv = *(const float4*)&S.Fy[n*LDF + h4];
        float4 pv = *(const float4*)&S.P[d][m*LDF + h4];
        s += fv.x*pv.x + fv.y*pv.y + fv.z*pv.z + fv.w*pv.w;
      }
      S.tmp[d*64 + l] = s;
    }
    __syncthreads();
    if (t < 64){
      float g1 = S.tmp[t]*gamma;
      float g2 = (S.tmp[t] - S.tmp[64 + t])*gamma;
      unsigned short h1 = f2bf(g1), l1 = f2bf(g1 - bf2f(h1));
      unsigned short h2 = f2bf(g2), l2 = f2bf(g2 - bf2f(h2));
      size_t o1 = pk(b, t, 36);
      size_t o2 = pk(b, 64 + t, 36);
      st_short_sc(rout + o1, h1); st_short_sc(rout + o1 + planeE, l1);
      st_short_sc(rout + o2, h2); st_short_sc(rout + o2 + planeE, l2);
    }
  }
}

// ---------------- MFMA GEMM phase: reg-staged sc loads, counted vmcnt, 2-buf LDS ----------------
template<int KB>
__device__ void gemm_phase(unsigned char (&lds)[2][8192],
    const unsigned short* __restrict__ Wh, const unsigned short* __restrict__ Wl,
    const unsigned short* __restrict__ act, int actPlane,
    const float4* __restrict__ bias4, const float* __restrict__ c_in,
    float* __restrict__ h_f32, float* __restrict__ c_out,
    unsigned short* __restrict__ out0, int KB0, int off0, int plane0,
    unsigned short* __restrict__ out1, int KB1, int off1, int plane1)
{
  const int tid = threadIdx.x, lane = tid & 63, w = tid >> 6;
  const int mt = blockIdx.x & 31, nt = blockIdx.x >> 5;
  const int fm = w & 3, fn0 = (w >> 2) << 1;

  const char* whp = (const char*)Wh + (((size_t)(mt*4+fm)*KB)*64 + lane)*16;
  const char* wlp = (const char*)Wl + (((size_t)(mt*4+fm)*KB)*64 + lane)*16;
  const char* ast = (const char*)act + (size_t)(w & 1)*((size_t)actPlane*2)
                  + ((size_t)(nt*4 + (w >> 1))*KB)*1024 + (size_t)lane*16;

  const int j0 = (mt*4+fm)*4 + (lane >> 4);
  float4 bb = bias4[j0];
  f32x4 acc0 = {bb.x, bb.y, bb.z, bb.w};
  f32x4 acc1 = acc0;

  uint4 ra[2], wh[3], wl[3];
  const int myoff = w*1024 + lane*16;

  // group 0
  ra[0] = ld_x4_sc(ast);
  wh[0] = ld_x4(whp);
  wl[0] = ld_x4(wlp);
  __builtin_amdgcn_sched_barrier(0);
  // group 1
  ra[1] = ld_x4_sc(ast + 1024);
  wh[1] = ld_x4(whp + 1024);
  wl[1] = ld_x4(wlp + 1024);
  __builtin_amdgcn_sched_barrier(0);
  asm volatile("s_waitcnt vmcnt(3)" ::: "memory");   // group 0 landed
  __builtin_amdgcn_sched_barrier(0);
  *(uint4*)&lds[0][myoff] = ra[0];

  const size_t rdoff = (size_t)fn0*2048 + (size_t)lane*16;

  #pragma unroll
  for (int kb = 0; kb < KB; kb++){
    asm volatile("s_waitcnt lgkmcnt(0)" ::: "memory");
    __builtin_amdgcn_s_barrier();
    __builtin_amdgcn_sched_barrier(0);
    if (kb + 2 < KB){
      ra[kb & 1]     = ld_x4_sc(ast + (size_t)(kb+2)*1024);
      wh[(kb+2) % 3] = ld_x4(whp + (size_t)(kb+2)*1024);
      wl[(kb+2) % 3] = ld_x4(wlp + (size_t)(kb+2)*1024);
      __builtin_amdgcn_sched_barrier(0);
      asm volatile("s_waitcnt vmcnt(3)" ::: "memory");   // group kb+1 landed
    } else {
      asm volatile("s_waitcnt vmcnt(0)" ::: "memory");
    }
    __builtin_amdgcn_sched_barrier(0);
    if (kb + 1 < KB)
      *(uint4*)&lds[(kb+1) & 1][myoff] = ra[(kb+1) & 1];
    const unsigned char* rb = &lds[kb & 1][0] + rdoff;
    bf16x8 a0h = *(const bf16x8*)(rb);
    bf16x8 a0l = *(const bf16x8*)(rb + 1024);
    bf16x8 a1h = *(const bf16x8*)(rb + 2048);
    bf16x8 a1l = *(const bf16x8*)(rb + 3072);
    bf16x8 whv = *(bf16x8*)&wh[kb % 3];
    bf16x8 wlv = *(bf16x8*)&wl[kb % 3];
    acc0 = MFMA(whv, a0h, acc0);
    acc1 = MFMA(whv, a1h, acc1);
    acc0 = MFMA(wlv, a0h, acc0);
    acc1 = MFMA(wlv, a1h, acc1);
    acc0 = MFMA(whv, a0l, acc0);
    acc1 = MFMA(whv, a1l, acc1);
  }

  const int bb0 = nt*64 + fn0*16 + (lane & 15);
  #pragma unroll
  for (int n = 0; n < 2; n++){
    f32x4 g = n ? acc1 : acc0;
    int b = bb0 + n*16;
    float ig = sigf(g[0]);
    float fg = sigf(g[1]);
    float gg = tanhf(g[2]);
    float og = sigf(g[3]);
    float c2 = fg * c_in[(size_t)b*512 + j0] + ig * gg;
    float h  = og * tanhf(c2);
    c_out[(size_t)b*512 + j0] = c2;                 // block-private
    if (h_f32) st_dword_sc(h_f32 + (size_t)b*512 + j0, h);
    unsigned short hh = f2bf(h);
    unsigned short hl = f2bf(h - bf2f(hh));
    size_t o0 = pk(b, off0 + j0, KB0);
    st_short_sc(out0 + o0, hh); st_short_sc(out0 + o0 + plane0, hl);
    if (out1){
      size_t o1 = pk(b, off1 + j0, KB1);
      st_short_sc(out1 + o1, hh); st_short_sc(out1 + o1 + plane1, hl);
    }
  }
}

// ---------------- z GEMM phase: 8 waves, K split 2 kb/wave, LDS reduction ----------------
__device__ void zgemm_phase(float* zred,
    const unsigned short* __restrict__ Wzh, const unsigned short* __restrict__ Wzl,
    const unsigned short* __restrict__ az, int planeZ,
    const float* __restrict__ mu_b, const float* __restrict__ sig_b,
    const float* __restrict__ eps_t,
    unsigned short* __restrict__ actD, int planeD)
{
  const int tid = threadIdx.x, lane = tid & 63, w = tid >> 6;
  const int fmb = blockIdx.x & 7, cg = blockIdx.x >> 3;
  const char* azh = (const char*)az + (size_t)cg*16384 + (size_t)lane*16;
  const char* azl = (const char*)(az + planeZ) + (size_t)cg*16384 + (size_t)lane*16;
  const int kb0 = w*2;

  uint4 rh0 = ld_x4_sc(azh + (size_t)kb0*1024);
  uint4 rl0 = ld_x4_sc(azl + (size_t)kb0*1024);
  uint4 rh1 = ld_x4_sc(azh + (size_t)(kb0+1)*1024);
  uint4 rl1 = ld_x4_sc(azl + (size_t)(kb0+1)*1024);

  const bf16x8* wmh = (const bf16x8*)Wzh + (size_t)(fmb    *16)*64 + lane;
  const bf16x8* wml = (const bf16x8*)Wzl + (size_t)(fmb    *16)*64 + lane;
  const bf16x8* wsh = (const bf16x8*)Wzh + (size_t)((fmb+8)*16)*64 + lane;
  const bf16x8* wsl = (const bf16x8*)Wzl + (size_t)((fmb+8)*16)*64 + lane;
  bf16x8 m0h = wmh[kb0*64],     m0l = wml[kb0*64];
  bf16x8 s0h = wsh[kb0*64],     s0l = wsl[kb0*64];
  bf16x8 m1h = wmh[(kb0+1)*64], m1l = wml[(kb0+1)*64];
  bf16x8 s1h = wsh[(kb0+1)*64], s1l = wsl[(kb0+1)*64];

  asm volatile("s_waitcnt vmcnt(0)" ::: "memory");
  __builtin_amdgcn_sched_barrier(0);

  bf16x8 a0h = *(bf16x8*)&rh0, a0l = *(bf16x8*)&rl0;
  bf16x8 a1h = *(bf16x8*)&rh1, a1l = *(bf16x8*)&rl1;
  f32x4 am = {0.f,0.f,0.f,0.f}, as = {0.f,0.f,0.f,0.f};
  am = MFMA(m0h,a0h,am); am = MFMA(m0l,a0h,am); am = MFMA(m0h,a0l,am);
  as = MFMA(s0h,a0h,as); as = MFMA(s0l,a0h,as); as = MFMA(s0h,a0l,as);
  am = MFMA(m1h,a1h,am); am = MFMA(m1l,a1h,am); am = MFMA(m1h,a1l,am);
  as = MFMA(s1h,a1h,as); as = MFMA(s1l,a1h,as); as = MFMA(s1h,a1l,as);

  *(f32x4*)&zred[(size_t)(w*64+lane)*8]     = am;
  *(f32x4*)&zred[(size_t)(w*64+lane)*8 + 4] = as;
  __syncthreads();

  if (w == 0){
    const int r0 = fmb*16 + (lane >> 4)*4;
    float4 bm = *(const float4*)&mu_b[r0];
    float4 bs = *(const float4*)&sig_b[r0];
    f32x4 AM = {bm.x,bm.y,bm.z,bm.w};
    f32x4 AS = {bs.x,bs.y,bs.z,bs.w};
    #pragma unroll
    for (int v = 0; v < 8; v++){
      AM += *(f32x4*)&zred[(size_t)(v*64+lane)*8];
      AS += *(f32x4*)&zred[(size_t)(v*64+lane)*8 + 4];
    }
    const int b = cg*16 + (lane & 15);
    float4 ev = *(const float4*)&eps_t[(size_t)b*128 + r0];
    float e[4] = {ev.x, ev.y, ev.z, ev.w};
    union { unsigned short s[4]; unsigned long long u; } zh, zl;
    #pragma unroll
    for (int i = 0; i < 4; i++){
      float z = AM[i] + e[i]*__expf(AS[i]);
      unsigned short hi = f2bf(z);
      zh.s[i] = hi;
      zl.s[i] = f2bf(z - bf2f(hi));
    }
    size_t o = pk(b, r0, 20);
    st_dwordx2_sc(actD + o, zh.u);
    st_dwordx2_sc(actD + planeD + o, zl.u);
  }
}

// ---------------- mega kernel: all 16 steps, non-flushing grid barriers ----------------
struct MegaP {
  const unsigned short *WpEh, *WpEl, *WpDh, *WpDl, *Wzh, *Wzl;
  const float *bE, *bD, *WwT, *write_b, *attnW, *attn_b, *mu_b, *sig_b;
  const float *x, *eps;
  unsigned short *actE0, *actE1, *actD0, *actD1, *AZ;
  float *cE0, *cE1, *cD0, *cD1, *hD, *out;
  unsigned int *bar;
};

__global__ __launch_bounds__(512) void mega(MegaP P){
  __shared__ SMem sm;
  constexpr int PE = 512*1152, PD = 512*640, PZ = 512*512;
  unsigned short* actE[2] = {P.actE0, P.actE1};
  unsigned short* actD[2] = {P.actD0, P.actD1};
  float* cE[2] = {P.cE0, P.cE1};
  float* cD[2] = {P.cD0, P.cD1};
  const int tid = threadIdx.x;
  const int half = tid >> 8, t256 = tid & 255;
  const int b2 = blockIdx.x*2 + half;
  unsigned int sn = 0;

  // pre-loop glimpse (t=0): zero canvas, zero h_dec
  wg_phase(sm.wg[half], t256, b2, P.hD, P.WwT, P.write_b, P.attnW, P.attn_b,
           nullptr, nullptr, P.x, P.actE0, PE);
  grid_sync(P.bar, (++sn)*256);

  #pragma unroll 1
  for (int t = 0; t < 16; t++){
    const int cur = t & 1, nxt = cur ^ 1;

    gemm_phase<36>(sm.glds, P.WpEh, P.WpEl,
        actE[cur], PE, (const float4*)P.bE, cE[cur], nullptr, cE[nxt],
        P.AZ, 16, 0, PZ,
        actE[nxt], 36, 640, PE);
    grid_sync(P.bar, (++sn)*256);

    zgemm_phase(sm.zred, P.Wzh, P.Wzl, P.AZ, PZ,
                P.mu_b, P.sig_b, P.eps + (size_t)t*65536, actD[cur], PD);
    grid_sync(P.bar, (++sn)*256);

    gemm_phase<20>(sm.glds, P.WpDh, P.WpDl,
        actD[cur], PD, (const float4*)P.bD, cD[cur], P.hD, cD[nxt],
        actE[nxt], 36, 128, PE,
        actD[nxt], 20, 128, PD);
    grid_sync(P.bar, (++sn)*256);

    wg_phase(sm.wg[half], t256, b2, P.hD, P.WwT, P.write_b, P.attnW, P.attn_b,
             t ? (P.out + (size_t)(t-1)*2097152) : nullptr,
             P.out + (size_t)t*2097152, P.x,
             (t < 15) ? actE[nxt] : nullptr, PE);
    if (t < 15) grid_sync(P.bar, (++sn)*256);
  }
}

// ---------------- host launcher ----------------
extern "C" void kernel_launch(void* const* d_in, const int* in_sizes, int n_in,
                              void* d_out, int out_size, void* d_ws, size_t ws_size,
                              hipStream_t stream)
{
  (void)in_sizes; (void)n_in; (void)out_size; (void)ws_size;
  const float* x       = (const float*)d_in[0];
  const float* eps     = (const float*)d_in[1];
  const float* encWih  = (const float*)d_in[2];
  const float* encWhh  = (const float*)d_in[3];
  const float* enc_b   = (const float*)d_in[4];
  const float* muW     = (const float*)d_in[5];
  const float* mu_b    = (const float*)d_in[6];
  const float* sigW    = (const float*)d_in[7];
  const float* sig_b   = (const float*)d_in[8];
  const float* decWih  = (const float*)d_in[9];
  const float* decWhh  = (const float*)d_in[10];
  const float* dec_b   = (const float*)d_in[11];
  const float* writeW  = (const float*)d_in[12];
  const float* write_b = (const float*)d_in[13];
  const float* attnW   = (const float*)d_in[14];
  const float* attn_b  = (const float*)d_in[15];
  float* out = (float*)d_out;

  char* p = (char*)d_ws;
  auto alloc = [&](size_t bytes){ char* r = p; p += (bytes + 255) & ~(size_t)255; return r; };

  const int KE = 1152, KD = 640;
  const int PE = 512*KE, PD = 512*KD;
  const int T8E = 128*36*64, T8D = 128*20*64;

  unsigned short* WpEh = (unsigned short*)alloc((size_t)T8E*16);
  unsigned short* WpEl = (unsigned short*)alloc((size_t)T8E*16);
  unsigned short* WpDh = (unsigned short*)alloc((size_t)T8D*16);
  unsigned short* WpDl = (unsigned short*)alloc((size_t)T8D*16);
  unsigned short* Wzh  = (unsigned short*)alloc(16384*16);
  unsigned short* Wzl  = (unsigned short*)alloc(16384*16);
  float* bE  = (float*)alloc(2048*4);
  float* bD  = (float*)alloc(2048*4);
  float* WwT = (float*)alloc(512*64*4);
  // zero-init region: bar, actE0(hi+lo), actD0(hi+lo), hD, cE0, cD0
  char* z0 = p;
  unsigned int* bar = (unsigned int*)alloc(256);
  unsigned short* actE0 = (unsigned short*)alloc((size_t)2*PE*2);
  unsigned short* actD0 = (unsigned short*)alloc((size_t)2*PD*2);
  float* hD  = (float*)alloc(512*512*4);
  float* cE0 = (float*)alloc(512*512*4);
  float* cD0 = (float*)alloc(512*512*4);
  size_t zbytes = (size_t)(p - z0);
  unsigned short* actE1 = (unsigned short*)alloc((size_t)2*PE*2);
  unsigned short* actD1 = (unsigned short*)alloc((size_t)2*PD*2);
  unsigned short* AZ    = (unsigned short*)alloc((size_t)2*(512*512)*2);
  float* cE1 = (float*)alloc(512*512*4);
  float* cD1 = (float*)alloc(512*512*4);

  int tot;
  tot = T8E;   pack_w_mfma<<<(tot+255)/256,256,0,stream>>>(encWih, encWhh, 640, KE, WpEh, WpEl, tot);
  tot = T8D;   pack_w_mfma<<<(tot+255)/256,256,0,stream>>>(decWih, decWhh, 128, KD, WpDh, WpDl, tot);
  pack_wz_mfma<<<64,256,0,stream>>>(muW, sigW, Wzh, Wzl);
  tot = 2048;  reorder_gates<<<(tot+255)/256,256,0,stream>>>(enc_b, bE, 512, 1, tot);
  tot = 2048;  reorder_gates<<<(tot+255)/256,256,0,stream>>>(dec_b, bD, 512, 1, tot);
  tot = 512*64; transpose_ww<<<(tot+255)/256,256,0,stream>>>(writeW, WwT);
  tot = (int)(zbytes/4); zero_f<<<(tot+255)/256,256,0,stream>>>((float*)z0, tot);

  MegaP mp;
  mp.WpEh = WpEh; mp.WpEl = WpEl; mp.WpDh = WpDh; mp.WpDl = WpDl;
  mp.Wzh = Wzh; mp.Wzl = Wzl;
  mp.bE = bE; mp.bD = bD; mp.WwT = WwT; mp.write_b = write_b;
  mp.attnW = attnW; mp.attn_b = attn_b; mp.mu_b = mu_b; mp.sig_b = sig_b;
  mp.x = x; mp.eps = eps;
  mp.actE0 = actE0; mp.actE1 = actE1; mp.actD0 = actD0; mp.actD1 = actD1;
  mp.AZ = AZ;
  mp.cE0 = cE0; mp.cE1 = cE1; mp.cD0 = cD0; mp.cD1 = cD1;
  mp.hD = hD; mp.out = out; mp.bar = bar;

  mega<<<256,512,0,stream>>>(mp);
}

// Round 10
// 1150.225 us; speedup vs baseline: 4.0345x; 1.4789x over previous
//
#include <hip/hip_runtime.h>

#define LDF 68
#define EPSF 1e-8f
#define MFMA(A,B,C) __builtin_amdgcn_mfma_f32_16x16x32_bf16((A),(B),(C),0,0,0)

typedef __attribute__((ext_vector_type(8))) short bf16x8;
typedef __attribute__((ext_vector_type(4))) float f32x4;

__device__ __forceinline__ float sigf(float x){ return 1.0f/(1.0f + __expf(-x)); }

__device__ __forceinline__ unsigned short f2bf(float f){
  unsigned u = __float_as_uint(f);
  u += 0x7FFFu + ((u >> 16) & 1u);
  return (unsigned short)(u >> 16);
}
__device__ __forceinline__ float bf2f(unsigned short s){
  return __uint_as_float((unsigned)s << 16);
}

// packed-activation element index (u16 units) within one plane
__device__ __forceinline__ size_t pk(int b, int col, int KB){
  return ((((size_t)((b>>4)*KB + (col>>5)))*64) + (size_t)((b&15) + (((col>>3)&3)<<4)))*8 + (col&7);
}

__device__ __forceinline__ void gload_lds16(const void* g, void* l){
  __builtin_amdgcn_global_load_lds(
      (const __attribute__((address_space(1))) void*)g,
      (__attribute__((address_space(3))) void*)l, 16, 0, 0);
}

// ---- explicit-asm loads/stores for internal (same-dispatch) crossings ----
__device__ __forceinline__ uint4 ld_x4_sc(const void* p){   // device-coherent
  uint4 r;
  asm volatile("global_load_dwordx4 %0, %1, off sc0 sc1" : "=v"(r) : "v"(p));
  return r;
}
__device__ __forceinline__ uint4 ld_x4(const void* p){      // plain
  uint4 r;
  asm volatile("global_load_dwordx4 %0, %1, off" : "=v"(r) : "v"(p));
  return r;
}
__device__ __forceinline__ void st_short_sc(void* p, unsigned short v){
  unsigned int vv = v;
  asm volatile("global_store_short %0, %1, off sc0 sc1" :: "v"(p), "v"(vv) : "memory");
}
__device__ __forceinline__ void st_dword_sc(void* p, float v){
  asm volatile("global_store_dword %0, %1, off sc0 sc1" :: "v"(p), "v"(v) : "memory");
}
__device__ __forceinline__ void st_dwordx2_sc(void* p, unsigned long long v){
  asm volatile("global_store_dwordx2 %0, %1, off sc0 sc1" :: "v"(p), "v"(v) : "memory");
}

// ---------------- init kernels ----------------
__global__ void reorder_gates(const float* __restrict__ src, float* __restrict__ dst,
                              int H, int K, int total){
  int idx = blockIdx.x*256 + threadIdx.x;
  if (idx >= total) return;
  int row = idx / K;
  int col = idx - row*K;
  int j = row >> 2, g = row & 3;
  dst[idx] = src[(size_t)(g*H + j)*K + col];
}

__global__ void pack_w_mfma(const float* __restrict__ Wih, const float* __restrict__ Whh,
                            int K_ih, int K_tot,
                            unsigned short* __restrict__ dhi, unsigned short* __restrict__ dlo,
                            int total8){
  int idx = blockIdx.x*256 + threadIdx.x;
  if (idx >= total8) return;
  int lane = idx & 63;
  int rest = idx >> 6;
  int KB = K_tot >> 5;
  int kb = rest % KB;
  int fm = rest / KB;
  int rr = fm*16 + (lane & 15);
  int orow = (rr & 3)*512 + (rr >> 2);     // gate reorder fused
  int k0 = kb*32 + (lane >> 4)*8;
  union { unsigned short s[8]; uint4 u; } vh, vl;
  #pragma unroll
  for (int i = 0; i < 8; i++){
    int k = k0 + i;
    float f = (k < K_ih) ? Wih[(size_t)orow*K_ih + k]
                         : Whh[(size_t)orow*512 + (k - K_ih)];
    unsigned short hi = f2bf(f);
    vh.s[i] = hi;
    vl.s[i] = f2bf(f - bf2f(hi));
  }
  *(uint4*)(dhi + (size_t)idx*8) = vh.u;
  *(uint4*)(dlo + (size_t)idx*8) = vl.u;
}

__global__ void pack_wz_mfma(const float* __restrict__ muW, const float* __restrict__ sigW,
                             unsigned short* __restrict__ dhi, unsigned short* __restrict__ dlo){
  int idx = blockIdx.x*256 + threadIdx.x;
  if (idx >= 16384) return;
  int lane = idx & 63, rest = idx >> 6;
  int kb = rest & 15, fmf = rest >> 4;
  int row = fmf*16 + (lane & 15);
  const float* src = (row < 128) ? (muW + (size_t)row*512) : (sigW + (size_t)(row-128)*512);
  int k0 = kb*32 + (lane >> 4)*8;
  union { unsigned short s[8]; uint4 u; } vh, vl;
  #pragma unroll
  for (int i = 0; i < 8; i++){
    float f = src[k0 + i];
    unsigned short hi = f2bf(f);
    vh.s[i] = hi;
    vl.s[i] = f2bf(f - bf2f(hi));
  }
  *(uint4*)(dhi + (size_t)idx*8) = vh.u;
  *(uint4*)(dlo + (size_t)idx*8) = vl.u;
}

__global__ void transpose_ww(const float* __restrict__ W, float* __restrict__ dst){
  int idx = blockIdx.x*256 + threadIdx.x;
  if (idx >= 512*64) return;
  int k = idx >> 6, n = idx & 63;
  dst[idx] = W[n*512 + k];
}

__global__ void zero_f(float* p, int n){
  int idx = blockIdx.x*256 + threadIdx.x;
  if (idx < n) p[idx] = 0.f;
}

// ---------------- grid barrier (relaxed atomics; per-dispatch fresh cell) ----------------
__device__ __forceinline__ void grid_sync(unsigned int* cell){
  asm volatile("s_waitcnt vmcnt(0) lgkmcnt(0)" ::: "memory");
  __syncthreads();
  if (threadIdx.x == 0){
    __hip_atomic_fetch_add(cell, 1u, __ATOMIC_RELAXED, __HIP_MEMORY_SCOPE_AGENT);
    while (__hip_atomic_load(cell, __ATOMIC_RELAXED, __HIP_MEMORY_SCOPE_AGENT) < 256u)
      __builtin_amdgcn_s_sleep(2);
  }
  __syncthreads();
}

// ---------------- stepA: enc GEMM (R6-style, plain loads/stores, no barrier) ----------------
template<int KB>
__global__ __launch_bounds__(512) void mfma_gemm_lstm(
    const bf16x8* __restrict__ Wh, const bf16x8* __restrict__ Wl,
    const unsigned short* __restrict__ act, int actPlane,
    const float4* __restrict__ bias4, const float* __restrict__ c_in,
    float* __restrict__ h_f32, float* __restrict__ c_out,
    unsigned short* __restrict__ out0, int KB0, int off0, int plane0,
    unsigned short* __restrict__ out1, int KB1, int off1, int plane1)
{
  __shared__ __align__(16) unsigned char lds[3][8192];
  const int tid = threadIdx.x, lane = tid & 63, w = tid >> 6;
  const int mt = blockIdx.x & 31, nt = blockIdx.x >> 5;
  const int fm = w & 3, fn0 = (w >> 2) << 1;

  const bf16x8* whp = Wh + ((size_t)(mt*4+fm)*KB)*64 + lane;
  const bf16x8* wlp = Wl + ((size_t)(mt*4+fm)*KB)*64 + lane;
  const char* ast = (const char*)act + (size_t)(w & 1)*((size_t)actPlane*2)
                  + ((size_t)(nt*4 + (w >> 1))*KB)*1024 + (size_t)lane*16;

  const int j0 = (mt*4+fm)*4 + (lane >> 4);
  float4 bb = bias4[j0];
  f32x4 acc0 = {bb.x, bb.y, bb.z, bb.w};
  f32x4 acc1 = acc0;

  gload_lds16(ast, (char*)&lds[0][w*1024]);
  bf16x8 whA = whp[0], wlA = wlp[0];
  __builtin_amdgcn_sched_barrier(0);
  asm volatile("" ::: "memory");
  gload_lds16(ast + 1024, (char*)&lds[1][w*1024]);
  bf16x8 whB = whp[64], wlB = wlp[64];
  __builtin_amdgcn_sched_barrier(0);
  asm volatile("" ::: "memory");

  const size_t rdoff = (size_t)fn0*2048 + (size_t)lane*16;

  #pragma unroll
  for (int kb = 0; kb < KB; kb++){
    if (kb + 1 < KB) asm volatile("s_waitcnt vmcnt(3)" ::: "memory");
    else             asm volatile("s_waitcnt vmcnt(0)" ::: "memory");
    __builtin_amdgcn_s_barrier();
    asm volatile("" ::: "memory");
    __builtin_amdgcn_sched_barrier(0);
    bf16x8 whC = whA, wlC = wlA;
    if (kb + 2 < KB){
      gload_lds16(ast + (size_t)(kb+2)*1024, (char*)&lds[(kb+2)%3][w*1024]);
      whC = whp[(kb+2)*64]; wlC = wlp[(kb+2)*64];
    }
    const unsigned char* rb = &lds[kb%3][0] + rdoff;
    bf16x8 a0h = *(const bf16x8*)(rb);
    bf16x8 a0l = *(const bf16x8*)(rb + 1024);
    bf16x8 a1h = *(const bf16x8*)(rb + 2048);
    bf16x8 a1l = *(const bf16x8*)(rb + 3072);
    acc0 = MFMA(whA, a0h, acc0);
    acc1 = MFMA(whA, a1h, acc1);
    acc0 = MFMA(wlA, a0h, acc0);
    acc1 = MFMA(wlA, a1h, acc1);
    acc0 = MFMA(whA, a0l, acc0);
    acc1 = MFMA(whA, a1l, acc1);
    whA = whB; wlA = wlB; whB = whC; wlB = wlC;
  }

  const int bb0 = nt*64 + fn0*16 + (lane & 15);
  #pragma unroll
  for (int n = 0; n < 2; n++){
    f32x4 g = n ? acc1 : acc0;
    int b = bb0 + n*16;
    float ig = sigf(g[0]);
    float fg = sigf(g[1]);
    float gg = tanhf(g[2]);
    float og = sigf(g[3]);
    float c2 = fg * c_in[(size_t)b*512 + j0] + ig * gg;
    float h  = og * tanhf(c2);
    c_out[(size_t)b*512 + j0] = c2;
    if (h_f32) h_f32[(size_t)b*512 + j0] = h;
    unsigned short hh = f2bf(h);
    unsigned short hl = f2bf(h - bf2f(hh));
    size_t o0 = pk(b, off0 + j0, KB0);
    out0[o0] = hh; out0[o0 + plane0] = hl;
    if (out1){
      size_t o1 = pk(b, off1 + j0, KB1);
      out1[o1] = hh; out1[o1 + plane1] = hl;
    }
  }
}

// ---------------- dec GEMM (reg-staged; kb<SCKB loads sc; hD store sc) ----------------
template<int KB, int SCKB>
__device__ void gemm_regstage(unsigned char (&lds)[2][8192],
    const unsigned short* __restrict__ Wh, const unsigned short* __restrict__ Wl,
    const unsigned short* __restrict__ act, int actPlane,
    const float4* __restrict__ bias4, const float* __restrict__ c_in,
    float* __restrict__ h_sc, float* __restrict__ c_out,
    unsigned short* __restrict__ out0, int KB0, int off0, int plane0,
    unsigned short* __restrict__ out1, int KB1, int off1, int plane1)
{
  const int tid = threadIdx.x, lane = tid & 63, w = tid >> 6;
  const int mt = blockIdx.x & 31, nt = blockIdx.x >> 5;
  const int fm = w & 3, fn0 = (w >> 2) << 1;

  const char* whp = (const char*)Wh + (((size_t)(mt*4+fm)*KB)*64 + lane)*16;
  const char* wlp = (const char*)Wl + (((size_t)(mt*4+fm)*KB)*64 + lane)*16;
  const char* ast = (const char*)act + (size_t)(w & 1)*((size_t)actPlane*2)
                  + ((size_t)(nt*4 + (w >> 1))*KB)*1024 + (size_t)lane*16;

  const int j0 = (mt*4+fm)*4 + (lane >> 4);
  float4 bb = bias4[j0];
  f32x4 acc0 = {bb.x, bb.y, bb.z, bb.w};
  f32x4 acc1 = acc0;

  uint4 ra[2], wh[3], wl[3];
  const int myoff = w*1024 + lane*16;

  ra[0] = (0 < SCKB) ? ld_x4_sc(ast) : ld_x4(ast);
  wh[0] = ld_x4(whp);
  wl[0] = ld_x4(wlp);
  __builtin_amdgcn_sched_barrier(0);
  ra[1] = (1 < SCKB) ? ld_x4_sc(ast + 1024) : ld_x4(ast + 1024);
  wh[1] = ld_x4(whp + 1024);
  wl[1] = ld_x4(wlp + 1024);
  __builtin_amdgcn_sched_barrier(0);
  asm volatile("s_waitcnt vmcnt(3)" ::: "memory");
  __builtin_amdgcn_sched_barrier(0);
  *(uint4*)&lds[0][myoff] = ra[0];

  const size_t rdoff = (size_t)fn0*2048 + (size_t)lane*16;

  #pragma unroll
  for (int kb = 0; kb < KB; kb++){
    asm volatile("s_waitcnt lgkmcnt(0)" ::: "memory");
    __builtin_amdgcn_s_barrier();
    __builtin_amdgcn_sched_barrier(0);
    if (kb + 2 < KB){
      const char* ap = ast + (size_t)(kb+2)*1024;
      ra[kb & 1]     = (kb + 2 < SCKB) ? ld_x4_sc(ap) : ld_x4(ap);
      wh[(kb+2) % 3] = ld_x4(whp + (size_t)(kb+2)*1024);
      wl[(kb+2) % 3] = ld_x4(wlp + (size_t)(kb+2)*1024);
      __builtin_amdgcn_sched_barrier(0);
      asm volatile("s_waitcnt vmcnt(3)" ::: "memory");
    } else {
      asm volatile("s_waitcnt vmcnt(0)" ::: "memory");
    }
    __builtin_amdgcn_sched_barrier(0);
    if (kb + 1 < KB)
      *(uint4*)&lds[(kb+1) & 1][myoff] = ra[(kb+1) & 1];
    const unsigned char* rb = &lds[kb & 1][0] + rdoff;
    bf16x8 a0h = *(const bf16x8*)(rb);
    bf16x8 a0l = *(const bf16x8*)(rb + 1024);
    bf16x8 a1h = *(const bf16x8*)(rb + 2048);
    bf16x8 a1l = *(const bf16x8*)(rb + 3072);
    bf16x8 whv = *(bf16x8*)&wh[kb % 3];
    bf16x8 wlv = *(bf16x8*)&wl[kb % 3];
    acc0 = MFMA(whv, a0h, acc0);
    acc1 = MFMA(whv, a1h, acc1);
    acc0 = MFMA(wlv, a0h, acc0);
    acc1 = MFMA(wlv, a1h, acc1);
    acc0 = MFMA(whv, a0l, acc0);
    acc1 = MFMA(whv, a1l, acc1);
  }

  const int bb0 = nt*64 + fn0*16 + (lane & 15);
  #pragma unroll
  for (int n = 0; n < 2; n++){
    f32x4 g = n ? acc1 : acc0;
    int b = bb0 + n*16;
    float ig = sigf(g[0]);
    float fg = sigf(g[1]);
    float gg = tanhf(g[2]);
    float og = sigf(g[3]);
    float c2 = fg * c_in[(size_t)b*512 + j0] + ig * gg;
    float h  = og * tanhf(c2);
    c_out[(size_t)b*512 + j0] = c2;
    st_dword_sc(h_sc + (size_t)b*512 + j0, h);   // consumed by wg after barrier
    unsigned short hh = f2bf(h);
    unsigned short hl = f2bf(h - bf2f(hh));
    size_t o0 = pk(b, off0 + j0, KB0);
    out0[o0] = hh; out0[o0 + plane0] = hl;
    size_t o1 = pk(b, off1 + j0, KB1);
    out1[o1] = hh; out1[o1 + plane1] = hl;
  }
}

// ---------------- z GEMM (8 waves; AZ plain; actD stores sc) ----------------
__device__ void zgemm_phase(float* zred,
    const unsigned short* __restrict__ Wzh, const unsigned short* __restrict__ Wzl,
    const unsigned short* __restrict__ az, int planeZ,
    const float* __restrict__ mu_b, const float* __restrict__ sig_b,
    const float* __restrict__ eps_t,
    unsigned short* __restrict__ actD, int planeD)
{
  const int tid = threadIdx.x, lane = tid & 63, w = tid >> 6;
  const int fmb = blockIdx.x & 7, cg = blockIdx.x >> 3;
  const char* azh = (const char*)az + (size_t)cg*16384 + (size_t)lane*16;
  const char* azl = (const char*)(az + planeZ) + (size_t)cg*16384 + (size_t)lane*16;
  const int kb0 = w*2;

  uint4 rh0 = ld_x4(azh + (size_t)kb0*1024);
  uint4 rl0 = ld_x4(azl + (size_t)kb0*1024);
  uint4 rh1 = ld_x4(azh + (size_t)(kb0+1)*1024);
  uint4 rl1 = ld_x4(azl + (size_t)(kb0+1)*1024);

  const bf16x8* wmh = (const bf16x8*)Wzh + (size_t)(fmb    *16)*64 + lane;
  const bf16x8* wml = (const bf16x8*)Wzl + (size_t)(fmb    *16)*64 + lane;
  const bf16x8* wsh = (const bf16x8*)Wzh + (size_t)((fmb+8)*16)*64 + lane;
  const bf16x8* wsl = (const bf16x8*)Wzl + (size_t)((fmb+8)*16)*64 + lane;
  bf16x8 m0h = wmh[kb0*64],     m0l = wml[kb0*64];
  bf16x8 s0h = wsh[kb0*64],     s0l = wsl[kb0*64];
  bf16x8 m1h = wmh[(kb0+1)*64], m1l = wml[(kb0+1)*64];
  bf16x8 s1h = wsh[(kb0+1)*64], s1l = wsl[(kb0+1)*64];

  asm volatile("s_waitcnt vmcnt(0)" ::: "memory");
  __builtin_amdgcn_sched_barrier(0);

  bf16x8 a0h = *(bf16x8*)&rh0, a0l = *(bf16x8*)&rl0;
  bf16x8 a1h = *(bf16x8*)&rh1, a1l = *(bf16x8*)&rl1;
  f32x4 am = {0.f,0.f,0.f,0.f}, as = {0.f,0.f,0.f,0.f};
  am = MFMA(m0h,a0h,am); am = MFMA(m0l,a0h,am); am = MFMA(m0h,a0l,am);
  as = MFMA(s0h,a0h,as); as = MFMA(s0l,a0h,as); as = MFMA(s0h,a0l,as);
  am = MFMA(m1h,a1h,am); am = MFMA(m1l,a1h,am); am = MFMA(m1h,a1l,am);
  as = MFMA(s1h,a1h,as); as = MFMA(s1l,a1h,as); as = MFMA(s1h,a1l,as);

  *(f32x4*)&zred[(size_t)(w*64+lane)*8]     = am;
  *(f32x4*)&zred[(size_t)(w*64+lane)*8 + 4] = as;
  __syncthreads();

  if (w == 0){
    const int r0 = fmb*16 + (lane >> 4)*4;
    float4 bm = *(const float4*)&mu_b[r0];
    float4 bs = *(const float4*)&sig_b[r0];
    f32x4 AM = {bm.x,bm.y,bm.z,bm.w};
    f32x4 AS = {bs.x,bs.y,bs.z,bs.w};
    #pragma unroll
    for (int v = 0; v < 8; v++){
      AM += *(f32x4*)&zred[(size_t)(v*64+lane)*8];
      AS += *(f32x4*)&zred[(size_t)(v*64+lane)*8 + 4];
    }
    const int b = cg*16 + (lane & 15);
    float4 ev = *(const float4*)&eps_t[(size_t)b*128 + r0];
    float e[4] = {ev.x, ev.y, ev.z, ev.w};
    union { unsigned short s[4]; unsigned long long u; } zh, zl;
    #pragma unroll
    for (int i = 0; i < 4; i++){
      float z = AM[i] + e[i]*__expf(AS[i]);
      unsigned short hi = f2bf(z);
      zh.s[i] = hi;
      zl.s[i] = f2bf(z - bf2f(hi));
    }
    size_t o = pk(b, r0, 20);
    st_dwordx2_sc(actD + o, zh.u);
    st_dwordx2_sc(actD + planeD + o, zl.u);
  }
}

// ---------------- wg (write + next glimpse), one batch per 256-thread half ----------------
struct WgS {
  float hs[512];
  float Fx[8*LDF], Fy[8*LDF], pl[8];
  float cs[64*LDF];
  float img_s[64*LDF];
  float P[2][8*LDF];
  float ps[4][64], w_s[64];
  float tmp[64*8];
};

__device__ void attn_window2(WgS& S, int t,
                             const float* __restrict__ attn_W,
                             const float* __restrict__ attn_b)
{
  int lane = t & 63, wid = t >> 6;
  for (int q = wid; q < 5; q += 4){
    float s = 0.f;
    for (int k = lane; k < 512; k += 64) s += S.hs[k]*attn_W[q*512 + k];
    for (int m = 32; m; m >>= 1) s += __shfl_xor(s, m);
    if (lane == 0) S.pl[q] = s + attn_b[q];
  }
  __syncthreads();
  float gx    = 32.5f*(S.pl[0] + 1.f);
  float gy    = 32.5f*(S.pl[1] + 1.f);
  float s2    = __expf(S.pl[2]);
  float delta = 9.f*__expf(S.pl[3]);
  float inv2  = 1.f/(2.f*s2);
  int n = t >> 5, a = t & 31;
  float mux = gx + ((float)n - 4.5f)*delta;
  float muy = gy + ((float)n - 4.5f)*delta;
  float dx0 = (float)a      - mux, dx1 = (float)(a+32) - mux;
  float dy0 = (float)a      - muy, dy1 = (float)(a+32) - muy;
  float e0 = __expf(-dx0*dx0*inv2), e1 = __expf(-dx1*dx1*inv2);
  float f0 = __expf(-dy0*dy0*inv2), f1 = __expf(-dy1*dy1*inv2);
  float sx = e0 + e1, sy = f0 + f1;
  for (int m = 16; m; m >>= 1){ sx += __shfl_xor(sx, m); sy += __shfl_xor(sy, m); }
  float rx = 1.f/(sx + EPSF), ry = 1.f/(sy + EPSF);
  S.Fx[n*LDF + a]      = e0*rx;  S.Fx[n*LDF + a + 32] = e1*rx;
  S.Fy[n*LDF + a]      = f0*ry;  S.Fy[n*LDF + a + 32] = f1*ry;
  __syncthreads();
}

__device__ void wg_phase(WgS& S, int t, int b,
    const float* __restrict__ h_dec,          // internal crossing -> sc load
    const float* __restrict__ WwT, const float* __restrict__ write_b,
    const float* __restrict__ attn_W, const float* __restrict__ attn_b,
    const float* __restrict__ canvas_prev, float* __restrict__ canvas_out,
    const float* __restrict__ x,
    unsigned short* __restrict__ rout, int planeE)
{
  uint4 rh = {0,0,0,0};
  if (t < 128)
    rh = ld_x4_sc((const char*)(h_dec + (size_t)b*512) + (size_t)t*16);
  if (rout){
    const float4* x4 = (const float4*)(x + (size_t)b*4096);
    for (int i = t; i < 1024; i += 256){
      int row = i >> 4, cb = (i & 15)*4;
      *(float4*)&S.img_s[row*LDF + cb] = x4[i];
    }
  }
  asm volatile("s_waitcnt vmcnt(0)" ::: "memory");
  __builtin_amdgcn_sched_barrier(0);
  if (t < 128) *(uint4*)&S.hs[t*4] = rh;
  __syncthreads();
  attn_window2(S, t, attn_W, attn_b);
  float gamma = __expf(S.pl[4]);

  if (canvas_out){
    {
      int j = t & 63, part = t >> 6;
      float s = 0.f;
      int kb = part*128;
      for (int k = 0; k < 128; k++) s += S.hs[kb + k] * WwT[(kb + k)*64 + j];
      S.ps[part][j] = s;
    }
    __syncthreads();
    if (t < 64)
      S.w_s[t] = write_b[t] + S.ps[0][t] + S.ps[1][t] + S.ps[2][t] + S.ps[3][t];
    __syncthreads();
    float inv_g = __expf(-S.pl[4]);
    #pragma unroll
    for (int e = 0; e < 2; e++){
      int gi = e*256 + t;
      int m = gi & 7, hh = gi >> 3;
      float s = 0.f;
      #pragma unroll
      for (int nn = 0; nn < 8; nn++) s += S.Fy[nn*LDF + hh] * S.w_s[nn*8 + m];
      S.tmp[hh*8 + m] = s;
    }
    __syncthreads();
    for (int e = 0; e < 16; e++){
      int idx = e*256 + t;
      int hh = idx >> 6, a = idx & 63;
      float s = 0.f;
      #pragma unroll
      for (int m = 0; m < 8; m++) s += S.tmp[hh*8 + m] * S.Fx[m*LDF + a];
      float prev = canvas_prev ? canvas_prev[(size_t)b*4096 + idx] : 0.f;
      float cv = prev + s*inv_g;
      canvas_out[(size_t)b*4096 + idx] = cv;
      S.cs[hh*LDF + a] = cv;
    }
  } else {
    for (int e = 0; e < 16; e++){
      int idx = e*256 + t;
      S.cs[(idx >> 6)*LDF + (idx & 63)] = 0.f;
    }
  }

  if (rout){
    __syncthreads();
    for (int e = 0; e < 16; e++){
      int idx = e*256 + t;
      int hh = idx >> 6, a = idx & 63;
      S.cs[hh*LDF + a] = sigf(S.cs[hh*LDF + a]);
    }
    __syncthreads();
    #pragma unroll
    for (int e = 0; e < 4; e++){
      int gi = e*256 + t;
      int d = gi >> 9, rem = gi & 511;
      int m = rem & 7, hh = rem >> 3;
      const float* Ssrc = d ? S.cs : S.img_s;
      float s = 0.f;
      #pragma unroll
      for (int w4 = 0; w4 < 64; w4 += 4){
        float4 iv = *(const float4*)&Ssrc[hh*LDF + w4];
        float4 fv = *(const float4*)&S.Fx[m*LDF + w4];
        s += iv.x*fv.x + iv.y*fv.y + iv.z*fv.z + iv.w*fv.w;
      }
      S.P[d][m*LDF + hh] = s;
    }
    __syncthreads();
    if (t < 128){
      int d = t >> 6, l = t & 63;
      int n = l >> 3, m = l & 7;
      float s = 0.f;
      #pragma unroll
      for (int h4 = 0; h4 < 64; h4 += 4){
        float4 fv = *(const float4*)&S.Fy[n*LDF + h4];
        float4 pv = *(const float4*)&S.P[d][m*LDF + h4];
        s += fv.x*pv.x + fv.y*pv.y + fv.z*pv.z + fv.w*pv.w;
      }
      S.tmp[d*64 + l] = s;
    }
    __syncthreads();
    if (t < 64){
      float g1 = S.tmp[t]*gamma;
      float g2 = (S.tmp[t] - S.tmp[64 + t])*gamma;
      unsigned short h1 = f2bf(g1), l1 = f2bf(g1 - bf2f(h1));
      unsigned short h2 = f2bf(g2), l2 = f2bf(g2 - bf2f(h2));
      size_t o1 = pk(b, t, 36);
      size_t o2 = pk(b, 64 + t, 36);
      rout[o1] = h1; rout[o1 + planeE] = l1;
      rout[o2] = h2; rout[o2 + planeE] = l2;
    }
  }
}

// ---------------- wg0: initial glimpse (t=0), standalone ----------------
__global__ __launch_bounds__(256) void wg0_kernel(
    const float* __restrict__ h_dec, const float* __restrict__ WwT,
    const float* __restrict__ write_b,
    const float* __restrict__ attn_W, const float* __restrict__ attn_b,
    const float* __restrict__ x, unsigned short* __restrict__ rout, int planeE)
{
  __shared__ WgS S;
  wg_phase(S, threadIdx.x, blockIdx.x, h_dec, WwT, write_b, attn_W, attn_b,
           nullptr, nullptr, x, rout, planeE);
}

// ---------------- stepB: z -> bar -> dec GEMM -> bar -> wg ----------------
struct BP {
  const unsigned short *WpDh, *WpDl, *Wzh, *Wzl;
  const unsigned short *actD_cur, *AZ;
  unsigned short *actE_nxt, *actD_nxt, *actD_cur_w;
  const float *bD, *cD_in, *mu_b, *sig_b, *eps_t;
  float *cD_out, *hD;
  const float *WwT, *write_b, *attnW, *attn_b, *x, *canvas_prev;
  float *canvas_out;
  unsigned short *rout;
  unsigned int *bar0, *bar1;
};

union SMemB {
  unsigned char glds[2][8192];
  float zred[8*64*8];
  WgS wg[2];
};

__global__ __launch_bounds__(512) void stepB(BP P){
  __shared__ SMemB sm;
  constexpr int PE = 512*1152, PD = 512*640, PZ = 512*512;

  zgemm_phase(sm.zred, P.Wzh, P.Wzl, P.AZ, PZ,
              P.mu_b, P.sig_b, P.eps_t, P.actD_cur_w, PD);
  grid_sync(P.bar0);

  gemm_regstage<20,4>(sm.glds, P.WpDh, P.WpDl, P.actD_cur, PD,
      (const float4*)P.bD, P.cD_in, P.hD, P.cD_out,
      P.actE_nxt, 36, 128, PE,
      P.actD_nxt, 20, 128, PD);
  grid_sync(P.bar1);

  const int tid = threadIdx.x;
  const int half = tid >> 8, t256 = tid & 255;
  const int b2 = blockIdx.x*2 + half;
  wg_phase(sm.wg[half], t256, b2, P.hD, P.WwT, P.write_b, P.attnW, P.attn_b,
           P.canvas_prev, P.canvas_out, P.x, P.rout, PE);
}

// ---------------- host launcher ----------------
extern "C" void kernel_launch(void* const* d_in, const int* in_sizes, int n_in,
                              void* d_out, int out_size, void* d_ws, size_t ws_size,
                              hipStream_t stream)
{
  (void)in_sizes; (void)n_in; (void)out_size; (void)ws_size;
  const float* x       = (const float*)d_in[0];
  const float* eps     = (const float*)d_in[1];
  const float* encWih  = (const float*)d_in[2];
  const float* encWhh  = (const float*)d_in[3];
  const float* enc_b   = (const float*)d_in[4];
  const float* muW     = (const float*)d_in[5];
  const float* mu_b    = (const float*)d_in[6];
  const float* sigW    = (const float*)d_in[7];
  const float* sig_b   = (const float*)d_in[8];
  const float* decWih  = (const float*)d_in[9];
  const float* decWhh  = (const float*)d_in[10];
  const float* dec_b   = (const float*)d_in[11];
  const float* writeW  = (const float*)d_in[12];
  const float* write_b = (const float*)d_in[13];
  const float* attnW   = (const float*)d_in[14];
  const float* attn_b  = (const float*)d_in[15];
  float* out = (float*)d_out;

  char* p = (char*)d_ws;
  auto alloc = [&](size_t bytes){ char* r = p; p += (bytes + 255) & ~(size_t)255; return r; };

  const int KE = 1152, KD = 640;
  const int PE = 512*KE, PD = 512*KD, PZ = 512*512;
  const int T8E = 128*36*64, T8D = 128*20*64;

  unsigned short* WpEh = (unsigned short*)alloc((size_t)T8E*16);
  unsigned short* WpEl = (unsigned short*)alloc((size_t)T8E*16);
  unsigned short* WpDh = (unsigned short*)alloc((size_t)T8D*16);
  unsigned short* WpDl = (unsigned short*)alloc((size_t)T8D*16);
  unsigned short* Wzh  = (unsigned short*)alloc(16384*16);
  unsigned short* Wzl  = (unsigned short*)alloc(16384*16);
  float* bE  = (float*)alloc(2048*4);
  float* bD  = (float*)alloc(2048*4);
  float* WwT = (float*)alloc(512*64*4);
  // zero-init region: bar cells, actE0(hi+lo), actD0(hi+lo), hD, cE0, cD0
  char* z0 = p;
  unsigned int* bar = (unsigned int*)alloc(32*64);
  unsigned short* actE0 = (unsigned short*)alloc((size_t)2*PE*2);
  unsigned short* actD0 = (unsigned short*)alloc((size_t)2*PD*2);
  float* hD  = (float*)alloc(512*512*4);
  float* cE0 = (float*)alloc(512*512*4);
  float* cD0 = (float*)alloc(512*512*4);
  size_t zbytes = (size_t)(p - z0);
  unsigned short* actE1 = (unsigned short*)alloc((size_t)2*PE*2);
  unsigned short* actD1 = (unsigned short*)alloc((size_t)2*PD*2);
  unsigned short* AZ    = (unsigned short*)alloc((size_t)2*PZ*2);
  float* cE1 = (float*)alloc(512*512*4);
  float* cD1 = (float*)alloc(512*512*4);

  unsigned short* actE[2] = { actE0, actE1 };
  unsigned short* actD[2] = { actD0, actD1 };
  float* cEf[2] = { cE0, cE1 };
  float* cDf[2] = { cD0, cD1 };

  int tot;
  tot = T8E;   pack_w_mfma<<<(tot+255)/256,256,0,stream>>>(encWih, encWhh, 640, KE, WpEh, WpEl, tot);
  tot = T8D;   pack_w_mfma<<<(tot+255)/256,256,0,stream>>>(decWih, decWhh, 128, KD, WpDh, WpDl, tot);
  pack_wz_mfma<<<64,256,0,stream>>>(muW, sigW, Wzh, Wzl);
  tot = 2048;  reorder_gates<<<(tot+255)/256,256,0,stream>>>(enc_b, bE, 512, 1, tot);
  tot = 2048;  reorder_gates<<<(tot+255)/256,256,0,stream>>>(dec_b, bD, 512, 1, tot);
  tot = 512*64; transpose_ww<<<(tot+255)/256,256,0,stream>>>(writeW, WwT);
  tot = (int)(zbytes/4); zero_f<<<(tot+255)/256,256,0,stream>>>((float*)z0, tot);

  wg0_kernel<<<512,256,0,stream>>>(hD, WwT, write_b, attnW, attn_b, x, actE[0], PE);

  for (int t = 0; t < 16; t++){
    int cur = t & 1, nxt = cur ^ 1;

    // stepA: enc GEMM (plain, no barrier)
    mfma_gemm_lstm<36><<<256,512,0,stream>>>(
        (const bf16x8*)WpEh, (const bf16x8*)WpEl, actE[cur], PE,
        (const float4*)bE, cEf[cur], nullptr, cEf[nxt],
        AZ, 16, 0, PZ,
        actE[nxt], 36, 640, PE);

    // stepB: z -> bar -> dec -> bar -> wg
    BP bp;
    bp.WpDh = WpDh; bp.WpDl = WpDl; bp.Wzh = Wzh; bp.Wzl = Wzl;
    bp.actD_cur = actD[cur]; bp.AZ = AZ;
    bp.actE_nxt = actE[nxt]; bp.actD_nxt = actD[nxt]; bp.actD_cur_w = actD[cur];
    bp.bD = bD; bp.cD_in = cDf[cur]; bp.mu_b = mu_b; bp.sig_b = sig_b;
    bp.eps_t = eps + (size_t)t*65536;
    bp.cD_out = cDf[nxt]; bp.hD = hD;
    bp.WwT = WwT; bp.write_b = write_b; bp.attnW = attnW; bp.attn_b = attn_b;
    bp.x = x;
    bp.canvas_prev = t ? (out + (size_t)(t-1)*2097152) : nullptr;
    bp.canvas_out  = out + (size_t)t*2097152;
    bp.rout = (t < 15) ? actE[nxt] : nullptr;
    bp.bar0 = bar + (t*2)*16;
    bp.bar1 = bar + (t*2+1)*16;
    stepB<<<256,512,0,stream>>>(bp);
  }
}

// Round 11
// 995.894 us; speedup vs baseline: 4.6597x; 1.1550x over previous
//
#include <hip/hip_runtime.h>

#define LDF 68
#define EPSF 1e-8f
#define MFMA(A,B,C) __builtin_amdgcn_mfma_f32_16x16x32_bf16((A),(B),(C),0,0,0)

typedef __attribute__((ext_vector_type(8))) short bf16x8;
typedef __attribute__((ext_vector_type(4))) float f32x4;

__device__ __forceinline__ float sigf(float x){ return 1.0f/(1.0f + __expf(-x)); }

__device__ __forceinline__ unsigned short f2bf(float f){
  unsigned u = __float_as_uint(f);
  u += 0x7FFFu + ((u >> 16) & 1u);
  return (unsigned short)(u >> 16);
}
__device__ __forceinline__ float bf2f(unsigned short s){
  return __uint_as_float((unsigned)s << 16);
}

// packed-activation element index (u16 units) within one plane
__device__ __forceinline__ size_t pk(int b, int col, int KB){
  return ((((size_t)((b>>4)*KB + (col>>5)))*64) + (size_t)((b&15) + (((col>>3)&3)<<4)))*8 + (col&7);
}

__device__ __forceinline__ void gload_lds16(const void* g, void* l){
  __builtin_amdgcn_global_load_lds(
      (const __attribute__((address_space(1))) void*)g,
      (__attribute__((address_space(3))) void*)l, 16, 0, 0);
}

// ---------------- init kernels ----------------
__global__ void pack_w_mfma(const float* __restrict__ Wih, const float* __restrict__ Whh,
                            int K_ih, int K_tot,
                            unsigned short* __restrict__ dhi, unsigned short* __restrict__ dlo,
                            int total8){
  int idx = blockIdx.x*256 + threadIdx.x;
  if (idx >= total8) return;
  int lane = idx & 63;
  int rest = idx >> 6;
  int KB = K_tot >> 5;
  int kb = rest % KB;
  int fm = rest / KB;
  int rr = fm*16 + (lane & 15);
  int orow = (rr & 3)*512 + (rr >> 2);     // gate reorder fused
  int k0 = kb*32 + (lane >> 4)*8;
  union { unsigned short s[8]; uint4 u; } vh, vl;
  #pragma unroll
  for (int i = 0; i < 8; i++){
    int k = k0 + i;
    float f = (k < K_ih) ? Wih[(size_t)orow*K_ih + k]
                         : Whh[(size_t)orow*512 + (k - K_ih)];
    unsigned short hi = f2bf(f);
    vh.s[i] = hi;
    vl.s[i] = f2bf(f - bf2f(hi));
  }
  *(uint4*)(dhi + (size_t)idx*8) = vh.u;
  *(uint4*)(dlo + (size_t)idx*8) = vl.u;
}

// merged small init: bE | bD | WwT transpose | Wz pack
__global__ void init_misc(const float* __restrict__ enc_b, const float* __restrict__ dec_b,
                          const float* __restrict__ writeW,
                          const float* __restrict__ muW, const float* __restrict__ sigW,
                          float* __restrict__ bE, float* __restrict__ bD,
                          float* __restrict__ WwT,
                          unsigned short* __restrict__ Wzh, unsigned short* __restrict__ Wzl){
  int idx = blockIdx.x*256 + threadIdx.x;
  if (idx < 2048){
    bE[idx] = enc_b[(idx & 3)*512 + (idx >> 2)];
    return;
  }
  idx -= 2048;
  if (idx < 2048){
    bD[idx] = dec_b[(idx & 3)*512 + (idx >> 2)];
    return;
  }
  idx -= 2048;
  if (idx < 32768){
    int k = idx >> 6, n = idx & 63;
    WwT[idx] = writeW[n*512 + k];
    return;
  }
  idx -= 32768;
  if (idx < 16384){
    int lane = idx & 63, rest = idx >> 6;
    int kb = rest & 15, fmf = rest >> 4;
    int row = fmf*16 + (lane & 15);
    const float* src = (row < 128) ? (muW + (size_t)row*512) : (sigW + (size_t)(row-128)*512);
    int k0 = kb*32 + (lane >> 4)*8;
    union { unsigned short s[8]; uint4 u; } vh, vl;
    #pragma unroll
    for (int i = 0; i < 8; i++){
      float f = src[k0 + i];
      unsigned short hi = f2bf(f);
      vh.s[i] = hi;
      vl.s[i] = f2bf(f - bf2f(hi));
    }
    *(uint4*)(Wzh + (size_t)idx*8) = vh.u;
    *(uint4*)(Wzl + (size_t)idx*8) = vl.u;
  }
}

__global__ void zero_f(float* p, int n){
  int idx = blockIdx.x*256 + threadIdx.x;
  if (idx < n) p[idx] = 0.f;
}

// ---------------- MFMA GEMM: 128x64 tile, 8 waves (1 fm x 4 fn each) ----------------
// counted-vmcnt 3-deep pipeline, gload_lds act staging (identical to R6 staging)
template<int KB>
__global__ __launch_bounds__(512) void mfma_gemm_lstm(
    const bf16x8* __restrict__ Wh, const bf16x8* __restrict__ Wl,
    const unsigned short* __restrict__ act, int actPlane,
    const float4* __restrict__ bias4, const float* __restrict__ c_in,
    float* __restrict__ h_f32, float* __restrict__ c_out,
    unsigned short* __restrict__ out0, int KB0, int off0, int plane0,
    unsigned short* __restrict__ out1, int KB1, int off1, int plane1)
{
  __shared__ __align__(16) unsigned char lds[3][8192];
  const int tid = threadIdx.x, lane = tid & 63, w = tid >> 6;
  const int mt = blockIdx.x & 15, nt = blockIdx.x >> 4;   // 16 mt x 8 nt = 128 blocks

  const int fmg = mt*8 + w;                               // global 16-row frag id (0..127)
  const bf16x8* whp = Wh + ((size_t)fmg*KB)*64 + lane;
  const bf16x8* wlp = Wl + ((size_t)fmg*KB)*64 + lane;
  const char* ast = (const char*)act + (size_t)(w & 1)*((size_t)actPlane*2)
                  + ((size_t)(nt*4 + (w >> 1))*KB)*1024 + (size_t)lane*16;

  const int j0 = fmg*4 + (lane >> 4);
  float4 bb = bias4[j0];
  f32x4 acc[4];
  #pragma unroll
  for (int fn = 0; fn < 4; fn++){ acc[fn][0]=bb.x; acc[fn][1]=bb.y; acc[fn][2]=bb.z; acc[fn][3]=bb.w; }

  gload_lds16(ast, (char*)&lds[0][w*1024]);
  bf16x8 whA = whp[0], wlA = wlp[0];
  __builtin_amdgcn_sched_barrier(0);
  asm volatile("" ::: "memory");
  gload_lds16(ast + 1024, (char*)&lds[1][w*1024]);
  bf16x8 whB = whp[64], wlB = wlp[64];
  __builtin_amdgcn_sched_barrier(0);
  asm volatile("" ::: "memory");

  #pragma unroll
  for (int kb = 0; kb < KB; kb++){
    if (kb + 1 < KB) asm volatile("s_waitcnt vmcnt(3)" ::: "memory");
    else             asm volatile("s_waitcnt vmcnt(0)" ::: "memory");
    __builtin_amdgcn_s_barrier();
    asm volatile("" ::: "memory");
    __builtin_amdgcn_sched_barrier(0);
    bf16x8 whC = whA, wlC = wlA;
    if (kb + 2 < KB){
      gload_lds16(ast + (size_t)(kb+2)*1024, (char*)&lds[(kb+2)%3][w*1024]);
      whC = whp[(kb+2)*64]; wlC = wlp[(kb+2)*64];
    }
    const unsigned char* rb = &lds[kb%3][0] + (size_t)lane*16;
    #pragma unroll
    for (int fn = 0; fn < 4; fn++){
      bf16x8 ah = *(const bf16x8*)(rb + fn*2048);
      bf16x8 al = *(const bf16x8*)(rb + fn*2048 + 1024);
      acc[fn] = MFMA(whA, ah, acc[fn]);
      acc[fn] = MFMA(wlA, ah, acc[fn]);
      acc[fn] = MFMA(whA, al, acc[fn]);
    }
    whA = whB; wlA = wlB; whB = whC; wlB = wlC;
  }

  const int bbase = nt*64 + (lane & 15);
  #pragma unroll
  for (int fn = 0; fn < 4; fn++){
    f32x4 g = acc[fn];
    int b = bbase + fn*16;
    float ig = sigf(g[0]);
    float fg = sigf(g[1]);
    float gg = tanhf(g[2]);
    float og = sigf(g[3]);
    float c2 = fg * c_in[(size_t)b*512 + j0] + ig * gg;
    float h  = og * tanhf(c2);
    c_out[(size_t)b*512 + j0] = c2;
    if (h_f32) h_f32[(size_t)b*512 + j0] = h;
    unsigned short hh = f2bf(h);
    unsigned short hl = f2bf(h - bf2f(hh));
    size_t o0 = pk(b, off0 + j0, KB0);
    out0[o0] = hh; out0[o0 + plane0] = hl;
    if (out1){
      size_t o1 = pk(b, off1 + j0, KB1);
      out1[o1] = hh; out1[o1 + plane1] = hl;
    }
  }
}

// ---------------- z GEMM: 8 waves, K split 2 kb/wave, LDS reduction ----------------
__global__ __launch_bounds__(512) void zgemm8(
    const unsigned short* __restrict__ Wzh, const unsigned short* __restrict__ Wzl,
    const unsigned short* __restrict__ az, int planeZ,
    const float* __restrict__ mu_b, const float* __restrict__ sig_b,
    const float* __restrict__ eps_t,
    unsigned short* __restrict__ actD, int planeD)
{
  __shared__ float zred[8*64*8];
  const int tid = threadIdx.x, lane = tid & 63, w = tid >> 6;
  const int fmb = blockIdx.x & 7, cg = blockIdx.x >> 3;
  const char* azh = (const char*)az + (size_t)cg*16384 + (size_t)lane*16;
  const char* azl = (const char*)(az + planeZ) + (size_t)cg*16384 + (size_t)lane*16;
  const int kb0 = w*2;

  bf16x8 a0h = *(const bf16x8*)(azh + (size_t)kb0*1024);
  bf16x8 a0l = *(const bf16x8*)(azl + (size_t)kb0*1024);
  bf16x8 a1h = *(const bf16x8*)(azh + (size_t)(kb0+1)*1024);
  bf16x8 a1l = *(const bf16x8*)(azl + (size_t)(kb0+1)*1024);

  const bf16x8* wmh = (const bf16x8*)Wzh + (size_t)(fmb    *16)*64 + lane;
  const bf16x8* wml = (const bf16x8*)Wzl + (size_t)(fmb    *16)*64 + lane;
  const bf16x8* wsh = (const bf16x8*)Wzh + (size_t)((fmb+8)*16)*64 + lane;
  const bf16x8* wsl = (const bf16x8*)Wzl + (size_t)((fmb+8)*16)*64 + lane;
  bf16x8 m0h = wmh[kb0*64],     m0l = wml[kb0*64];
  bf16x8 s0h = wsh[kb0*64],     s0l = wsl[kb0*64];
  bf16x8 m1h = wmh[(kb0+1)*64], m1l = wml[(kb0+1)*64];
  bf16x8 s1h = wsh[(kb0+1)*64], s1l = wsl[(kb0+1)*64];

  f32x4 am = {0.f,0.f,0.f,0.f}, as = {0.f,0.f,0.f,0.f};
  am = MFMA(m0h,a0h,am); am = MFMA(m0l,a0h,am); am = MFMA(m0h,a0l,am);
  as = MFMA(s0h,a0h,as); as = MFMA(s0l,a0h,as); as = MFMA(s0h,a0l,as);
  am = MFMA(m1h,a1h,am); am = MFMA(m1l,a1h,am); am = MFMA(m1h,a1l,am);
  as = MFMA(s1h,a1h,as); as = MFMA(s1l,a1h,as); as = MFMA(s1h,a1l,as);

  *(f32x4*)&zred[(size_t)(w*64+lane)*8]     = am;
  *(f32x4*)&zred[(size_t)(w*64+lane)*8 + 4] = as;
  __syncthreads();

  if (w == 0){
    const int r0 = fmb*16 + (lane >> 4)*4;
    float4 bm = *(const float4*)&mu_b[r0];
    float4 bs = *(const float4*)&sig_b[r0];
    f32x4 AM = {bm.x,bm.y,bm.z,bm.w};
    f32x4 AS = {bs.x,bs.y,bs.z,bs.w};
    #pragma unroll
    for (int v = 0; v < 8; v++){
      AM += *(f32x4*)&zred[(size_t)(v*64+lane)*8];
      AS += *(f32x4*)&zred[(size_t)(v*64+lane)*8 + 4];
    }
    const int b = cg*16 + (lane & 15);
    float4 ev = *(const float4*)&eps_t[(size_t)b*128 + r0];
    float e[4] = {ev.x, ev.y, ev.z, ev.w};
    union { unsigned short s[4]; uint2 u; } zh, zl;
    #pragma unroll
    for (int i = 0; i < 4; i++){
      float z = AM[i] + e[i]*__expf(AS[i]);
      unsigned short hi = f2bf(z);
      zh.s[i] = hi;
      zl.s[i] = f2bf(z - bf2f(hi));
    }
    size_t o = pk(b, r0, 20);
    *(uint2*)(actD + o) = zh.u;
    *(uint2*)(actD + planeD + o) = zl.u;
  }
}

// ---------------- fused write(t) + glimpse(t+1) (R6 verbatim) ----------------
__device__ void attn_window(const float* __restrict__ h,
                            const float* __restrict__ attn_W,
                            const float* __restrict__ attn_b,
                            float* Fx, float* Fy, float* pl)
{
  int tid = threadIdx.x;
  int lane = tid & 63, wid = tid >> 6;
  for (int q = wid; q < 5; q += 4){
    float s = 0.f;
    for (int k = lane; k < 512; k += 64) s += h[k]*attn_W[q*512 + k];
    for (int m = 32; m; m >>= 1) s += __shfl_xor(s, m);
    if (lane == 0) pl[q] = s + attn_b[q];
  }
  __syncthreads();
  float gx    = 32.5f*(pl[0] + 1.f);
  float gy    = 32.5f*(pl[1] + 1.f);
  float s2    = __expf(pl[2]);
  float delta = 9.f*__expf(pl[3]);
  float inv2  = 1.f/(2.f*s2);
  int n = tid >> 5, a = tid & 31;
  float mux = gx + ((float)n - 4.5f)*delta;
  float muy = gy + ((float)n - 4.5f)*delta;
  float dx0 = (float)a      - mux, dx1 = (float)(a+32) - mux;
  float dy0 = (float)a      - muy, dy1 = (float)(a+32) - muy;
  float e0 = __expf(-dx0*dx0*inv2), e1 = __expf(-dx1*dx1*inv2);
  float f0 = __expf(-dy0*dy0*inv2), f1 = __expf(-dy1*dy1*inv2);
  float sx = e0 + e1, sy = f0 + f1;
  for (int m = 16; m; m >>= 1){ sx += __shfl_xor(sx, m); sy += __shfl_xor(sy, m); }
  float rx = 1.f/(sx + EPSF), ry = 1.f/(sy + EPSF);
  Fx[n*LDF + a]      = e0*rx;  Fx[n*LDF + a + 32] = e1*rx;
  Fy[n*LDF + a]      = f0*ry;  Fy[n*LDF + a + 32] = f1*ry;
  __syncthreads();
}

__global__ __launch_bounds__(256) void wg_kernel(
    const float* __restrict__ h_dec,
    const float* __restrict__ WwT, const float* __restrict__ write_b,
    const float* __restrict__ attn_W, const float* __restrict__ attn_b,
    const float* __restrict__ canvas_prev, float* __restrict__ canvas_out,
    const float* __restrict__ x,
    unsigned short* __restrict__ rout, int planeE)
{
  __shared__ float hs[512];
  __shared__ float Fx[8*LDF], Fy[8*LDF], pl[8];
  __shared__ float cs[64*LDF];
  __shared__ float img_s[64*LDF];
  __shared__ float P[2][8*LDF];
  __shared__ float ps[4][64], w_s[64];
  __shared__ float tmp[64*8];
  const int b = blockIdx.x, tid = threadIdx.x;

  for (int i = tid; i < 128; i += 256)
    ((float4*)hs)[i] = ((const float4*)(h_dec + (size_t)b*512))[i];
  if (rout){
    const float4* x4 = (const float4*)(x + (size_t)b*4096);
    for (int i = tid; i < 1024; i += 256){
      int row = i >> 4, cb = (i & 15)*4;
      *(float4*)&img_s[row*LDF + cb] = x4[i];
    }
  }
  __syncthreads();
  attn_window(hs, attn_W, attn_b, Fx, Fy, pl);
  float gamma = __expf(pl[4]);

  if (canvas_out){
    {
      int j = tid & 63, part = tid >> 6;
      float s = 0.f;
      int kb = part*128;
      for (int k = 0; k < 128; k++) s += hs[kb + k] * WwT[(kb + k)*64 + j];
      ps[part][j] = s;
    }
    __syncthreads();
    if (tid < 64)
      w_s[tid] = write_b[tid] + ps[0][tid] + ps[1][tid] + ps[2][tid] + ps[3][tid];
    __syncthreads();
    float inv_g = __expf(-pl[4]);
    #pragma unroll
    for (int e = 0; e < 2; e++){
      int gi = e*256 + tid;
      int m = gi & 7, hh = gi >> 3;
      float s = 0.f;
      #pragma unroll
      for (int nn = 0; nn < 8; nn++) s += Fy[nn*LDF + hh] * w_s[nn*8 + m];
      tmp[hh*8 + m] = s;
    }
    __syncthreads();
    for (int e = 0; e < 16; e++){
      int idx = e*256 + tid;
      int hh = idx >> 6, a = idx & 63;
      float s = 0.f;
      #pragma unroll
      for (int m = 0; m < 8; m++) s += tmp[hh*8 + m] * Fx[m*LDF + a];
      float prev = canvas_prev ? canvas_prev[(size_t)b*4096 + idx] : 0.f;
      float cv = prev + s*inv_g;
      canvas_out[(size_t)b*4096 + idx] = cv;
      cs[hh*LDF + a] = cv;
    }
  } else {
    for (int e = 0; e < 16; e++){
      int idx = e*256 + tid;
      cs[(idx >> 6)*LDF + (idx & 63)] = 0.f;
    }
  }
  if (!rout) return;
  __syncthreads();
  for (int e = 0; e < 16; e++){
    int idx = e*256 + tid;
    int hh = idx >> 6, a = idx & 63;
    cs[hh*LDF + a] = sigf(cs[hh*LDF + a]);
  }
  __syncthreads();
  #pragma unroll
  for (int e = 0; e < 4; e++){
    int gi = e*256 + tid;
    int d = gi >> 9, rem = gi & 511;
    int m = rem & 7, hh = rem >> 3;
    const float* S = d ? cs : img_s;
    float s = 0.f;
    #pragma unroll
    for (int w4 = 0; w4 < 64; w4 += 4){
      float4 iv = *(const float4*)&S[hh*LDF + w4];
      float4 fv = *(const float4*)&Fx[m*LDF + w4];
      s += iv.x*fv.x + iv.y*fv.y + iv.z*fv.z + iv.w*fv.w;
    }
    P[d][m*LDF + hh] = s;
  }
  __syncthreads();
  if (tid < 128){
    int d = tid >> 6, l = tid & 63;
    int n = l >> 3, m = l & 7;
    float s = 0.f;
    #pragma unroll
    for (int h4 = 0; h4 < 64; h4 += 4){
      float4 fv = *(const float4*)&Fy[n*LDF + h4];
      float4 pv = *(const float4*)&P[d][m*LDF + h4];
      s += fv.x*pv.x + fv.y*pv.y + fv.z*pv.z + fv.w*pv.w;
    }
    tmp[d*64 + l] = s;
  }
  __syncthreads();
  if (tid < 64){
    float g1 = tmp[tid]*gamma;
    float g2 = (tmp[tid] - tmp[64 + tid])*gamma;
    unsigned short h1 = f2bf(g1), l1 = f2bf(g1 - bf2f(h1));
    unsigned short h2 = f2bf(g2), l2 = f2bf(g2 - bf2f(h2));
    size_t o1 = pk(b, tid, 36);
    size_t o2 = pk(b, 64 + tid, 36);
    rout[o1] = h1; rout[o1 + planeE] = l1;
    rout[o2] = h2; rout[o2 + planeE] = l2;
  }
}

// ---------------- host launcher ----------------
extern "C" void kernel_launch(void* const* d_in, const int* in_sizes, int n_in,
                              void* d_out, int out_size, void* d_ws, size_t ws_size,
                              hipStream_t stream)
{
  (void)in_sizes; (void)n_in; (void)out_size; (void)ws_size;
  const float* x       = (const float*)d_in[0];
  const float* eps     = (const float*)d_in[1];
  const float* encWih  = (const float*)d_in[2];
  const float* encWhh  = (const float*)d_in[3];
  const float* enc_b   = (const float*)d_in[4];
  const float* muW     = (const float*)d_in[5];
  const float* mu_b    = (const float*)d_in[6];
  const float* sigW    = (const float*)d_in[7];
  const float* sig_b   = (const float*)d_in[8];
  const float* decWih  = (const float*)d_in[9];
  const float* decWhh  = (const float*)d_in[10];
  const float* dec_b   = (const float*)d_in[11];
  const float* writeW  = (const float*)d_in[12];
  const float* write_b = (const float*)d_in[13];
  const float* attnW   = (const float*)d_in[14];
  const float* attn_b  = (const float*)d_in[15];
  float* out = (float*)d_out;

  char* p = (char*)d_ws;
  auto alloc = [&](size_t bytes){ char* r = p; p += (bytes + 255) & ~(size_t)255; return r; };

  const int KE = 1152, KD = 640;
  const int PE = 512*KE, PD = 512*KD, PZ = 512*512;
  const int T8E = 128*36*64, T8D = 128*20*64;

  unsigned short* WpEh = (unsigned short*)alloc((size_t)T8E*16);
  unsigned short* WpEl = (unsigned short*)alloc((size_t)T8E*16);
  unsigned short* WpDh = (unsigned short*)alloc((size_t)T8D*16);
  unsigned short* WpDl = (unsigned short*)alloc((size_t)T8D*16);
  unsigned short* Wzh  = (unsigned short*)alloc(16384*16);
  unsigned short* Wzl  = (unsigned short*)alloc(16384*16);
  float* bE  = (float*)alloc(2048*4);
  float* bD  = (float*)alloc(2048*4);
  float* WwT = (float*)alloc(512*64*4);
  // zero-init region
  char* z0 = p;
  unsigned short* actE0 = (unsigned short*)alloc((size_t)2*PE*2);
  unsigned short* actD0 = (unsigned short*)alloc((size_t)2*PD*2);
  float* hDf = (float*)alloc(512*512*4);
  float* cE0 = (float*)alloc(512*512*4);
  float* cD0 = (float*)alloc(512*512*4);
  size_t zbytes = (size_t)(p - z0);
  unsigned short* actE1 = (unsigned short*)alloc((size_t)2*PE*2);
  unsigned short* actD1 = (unsigned short*)alloc((size_t)2*PD*2);
  unsigned short* AZ    = (unsigned short*)alloc((size_t)2*PZ*2);
  float* cE1 = (float*)alloc(512*512*4);
  float* cD1 = (float*)alloc(512*512*4);

  unsigned short* actE[2] = { actE0, actE1 };
  unsigned short* actD[2] = { actD0, actD1 };
  float* cEf[2] = { cE0, cE1 };
  float* cDf[2] = { cD0, cD1 };

  int tot;
  tot = T8E;   pack_w_mfma<<<(tot+255)/256,256,0,stream>>>(encWih, encWhh, 640, KE, WpEh, WpEl, tot);
  tot = T8D;   pack_w_mfma<<<(tot+255)/256,256,0,stream>>>(decWih, decWhh, 128, KD, WpDh, WpDl, tot);
  tot = 2048+2048+32768+16384;
  init_misc<<<(tot+255)/256,256,0,stream>>>(enc_b, dec_b, writeW, muW, sigW,
                                            bE, bD, WwT, Wzh, Wzl);
  tot = (int)(zbytes/4); zero_f<<<(tot+255)/256,256,0,stream>>>((float*)z0, tot);

  // pre-loop glimpse (t=0): zero canvas, zero h_dec
  wg_kernel<<<512,256,0,stream>>>(hDf, WwT, write_b, attnW, attn_b,
                                  nullptr, nullptr, x, actE[0], PE);

  for (int t = 0; t < 16; t++){
    int cur = t & 1, nxt = cur ^ 1;

    mfma_gemm_lstm<36><<<128,512,0,stream>>>(
        (const bf16x8*)WpEh, (const bf16x8*)WpEl, actE[cur], PE,
        (const float4*)bE, cEf[cur], nullptr, cEf[nxt],
        AZ, 16, 0, PZ,
        actE[nxt], 36, 640, PE);

    zgemm8<<<256,512,0,stream>>>(
        Wzh, Wzl, AZ, PZ, mu_b, sig_b,
        eps + (size_t)t*65536, actD[cur], PD);

    mfma_gemm_lstm<20><<<128,512,0,stream>>>(
        (const bf16x8*)WpDh, (const bf16x8*)WpDl, actD[cur], PD,
        (const float4*)bD, cDf[cur], hDf, cDf[nxt],
        actE[nxt], 36, 128, PE,
        actD[nxt], 20, 128, PD);

    wg_kernel<<<512,256,0,stream>>>(hDf, WwT, write_b, attnW, attn_b,
                                    t ? (out + (size_t)(t-1)*2097152) : nullptr,
                                    out + (size_t)t*2097152, x,
                                    (t < 15) ? actE[nxt] : nullptr, PE);
  }
}

// Round 12
// 881.162 us; speedup vs baseline: 5.2664x; 1.1302x over previous
//
#include <hip/hip_runtime.h>

#define LDF 68
#define EPSF 1e-8f
#define MFMA(A,B,C) __builtin_amdgcn_mfma_f32_16x16x32_bf16((A),(B),(C),0,0,0)

typedef __attribute__((ext_vector_type(8))) short bf16x8;
typedef __attribute__((ext_vector_type(4))) float f32x4;

__device__ __forceinline__ float sigf(float x){ return 1.0f/(1.0f + __expf(-x)); }

__device__ __forceinline__ unsigned short f2bf(float f){
  unsigned u = __float_as_uint(f);
  u += 0x7FFFu + ((u >> 16) & 1u);
  return (unsigned short)(u >> 16);
}
__device__ __forceinline__ float bf2f(unsigned short s){
  return __uint_as_float((unsigned)s << 16);
}

// packed-activation element index (u16 units) within one plane
__device__ __forceinline__ size_t pk(int b, int col, int KB){
  return ((((size_t)((b>>4)*KB + (col>>5)))*64) + (size_t)((b&15) + (((col>>3)&3)<<4)))*8 + (col&7);
}

__device__ __forceinline__ void gload_lds16(const void* g, void* l){
  __builtin_amdgcn_global_load_lds(
      (const __attribute__((address_space(1))) void*)g,
      (__attribute__((address_space(3))) void*)l, 16, 0, 0);
}

// ---------------- init kernels ----------------
__global__ void pack_w_mfma(const float* __restrict__ Wih, const float* __restrict__ Whh,
                            int K_ih, int K_tot,
                            unsigned short* __restrict__ dhi, unsigned short* __restrict__ dlo,
                            int total8){
  int idx = blockIdx.x*256 + threadIdx.x;
  if (idx >= total8) return;
  int lane = idx & 63;
  int rest = idx >> 6;
  int KB = K_tot >> 5;
  int kb = rest % KB;
  int fm = rest / KB;
  int rr = fm*16 + (lane & 15);
  int orow = (rr & 3)*512 + (rr >> 2);     // gate reorder fused
  int k0 = kb*32 + (lane >> 4)*8;
  union { unsigned short s[8]; uint4 u; } vh, vl;
  #pragma unroll
  for (int i = 0; i < 8; i++){
    int k = k0 + i;
    float f = (k < K_ih) ? Wih[(size_t)orow*K_ih + k]
                         : Whh[(size_t)orow*512 + (k - K_ih)];
    unsigned short hi = f2bf(f);
    vh.s[i] = hi;
    vl.s[i] = f2bf(f - bf2f(hi));
  }
  *(uint4*)(dhi + (size_t)idx*8) = vh.u;
  *(uint4*)(dlo + (size_t)idx*8) = vl.u;
}

// merged small init: bE | bD | WwT transpose | Wz pack
__global__ void init_misc(const float* __restrict__ enc_b, const float* __restrict__ dec_b,
                          const float* __restrict__ writeW,
                          const float* __restrict__ muW, const float* __restrict__ sigW,
                          float* __restrict__ bE, float* __restrict__ bD,
                          float* __restrict__ WwT,
                          unsigned short* __restrict__ Wzh, unsigned short* __restrict__ Wzl){
  int idx = blockIdx.x*256 + threadIdx.x;
  if (idx < 2048){
    bE[idx] = enc_b[(idx & 3)*512 + (idx >> 2)];
    return;
  }
  idx -= 2048;
  if (idx < 2048){
    bD[idx] = dec_b[(idx & 3)*512 + (idx >> 2)];
    return;
  }
  idx -= 2048;
  if (idx < 32768){
    int k = idx >> 6, n = idx & 63;
    WwT[idx] = writeW[n*512 + k];
    return;
  }
  idx -= 32768;
  if (idx < 16384){
    int lane = idx & 63, rest = idx >> 6;
    int kb = rest & 15, fmf = rest >> 4;
    int row = fmf*16 + (lane & 15);
    const float* src = (row < 128) ? (muW + (size_t)row*512) : (sigW + (size_t)(row-128)*512);
    int k0 = kb*32 + (lane >> 4)*8;
    union { unsigned short s[8]; uint4 u; } vh, vl;
    #pragma unroll
    for (int i = 0; i < 8; i++){
      float f = src[k0 + i];
      unsigned short hi = f2bf(f);
      vh.s[i] = hi;
      vl.s[i] = f2bf(f - bf2f(hi));
    }
    *(uint4*)(Wzh + (size_t)idx*8) = vh.u;
    *(uint4*)(Wzl + (size_t)idx*8) = vl.u;
  }
}

__global__ void zero_f(float* p, int n){
  int idx = blockIdx.x*256 + threadIdx.x;
  if (idx < n) p[idx] = 0.f;
}

// ---------------- MFMA GEMM: 64x64 tile, 256 blocks (R6-verified config) ----------------
// 8 waves (4 fm x 2 fn), counted-vmcnt 3-deep pipeline, gload_lds act staging
template<int KB>
__global__ __launch_bounds__(512) void mfma_gemm_lstm(
    const bf16x8* __restrict__ Wh, const bf16x8* __restrict__ Wl,
    const unsigned short* __restrict__ act, int actPlane,
    const float4* __restrict__ bias4, const float* __restrict__ c_in,
    float* __restrict__ h_f32, float* __restrict__ c_out,
    unsigned short* __restrict__ out0, int KB0, int off0, int plane0,
    unsigned short* __restrict__ out1, int KB1, int off1, int plane1)
{
  __shared__ __align__(16) unsigned char lds[3][8192];
  const int tid = threadIdx.x, lane = tid & 63, w = tid >> 6;
  const int mt = blockIdx.x & 31, nt = blockIdx.x >> 5;
  const int fm = w & 3, fn0 = (w >> 2) << 1;

  const bf16x8* whp = Wh + ((size_t)(mt*4+fm)*KB)*64 + lane;
  const bf16x8* wlp = Wl + ((size_t)(mt*4+fm)*KB)*64 + lane;
  const char* ast = (const char*)act + (size_t)(w & 1)*((size_t)actPlane*2)
                  + ((size_t)(nt*4 + (w >> 1))*KB)*1024 + (size_t)lane*16;

  const int j0 = (mt*4+fm)*4 + (lane >> 4);
  float4 bb = bias4[j0];
  f32x4 acc0 = {bb.x, bb.y, bb.z, bb.w};
  f32x4 acc1 = acc0;

  gload_lds16(ast, (char*)&lds[0][w*1024]);
  bf16x8 whA = whp[0], wlA = wlp[0];
  __builtin_amdgcn_sched_barrier(0);
  asm volatile("" ::: "memory");
  gload_lds16(ast + 1024, (char*)&lds[1][w*1024]);
  bf16x8 whB = whp[64], wlB = wlp[64];
  __builtin_amdgcn_sched_barrier(0);
  asm volatile("" ::: "memory");

  const size_t rdoff = (size_t)fn0*2048 + (size_t)lane*16;

  #pragma unroll
  for (int kb = 0; kb < KB; kb++){
    if (kb + 1 < KB) asm volatile("s_waitcnt vmcnt(3)" ::: "memory");
    else             asm volatile("s_waitcnt vmcnt(0)" ::: "memory");
    __builtin_amdgcn_s_barrier();
    asm volatile("" ::: "memory");
    __builtin_amdgcn_sched_barrier(0);
    bf16x8 whC = whA, wlC = wlA;
    if (kb + 2 < KB){
      gload_lds16(ast + (size_t)(kb+2)*1024, (char*)&lds[(kb+2)%3][w*1024]);
      whC = whp[(kb+2)*64]; wlC = wlp[(kb+2)*64];
    }
    const unsigned char* rb = &lds[kb%3][0] + rdoff;
    bf16x8 a0h = *(const bf16x8*)(rb);
    bf16x8 a0l = *(const bf16x8*)(rb + 1024);
    bf16x8 a1h = *(const bf16x8*)(rb + 2048);
    bf16x8 a1l = *(const bf16x8*)(rb + 3072);
    acc0 = MFMA(whA, a0h, acc0);
    acc1 = MFMA(whA, a1h, acc1);
    acc0 = MFMA(wlA, a0h, acc0);
    acc1 = MFMA(wlA, a1h, acc1);
    acc0 = MFMA(whA, a0l, acc0);
    acc1 = MFMA(whA, a1l, acc1);
    whA = whB; wlA = wlB; whB = whC; wlB = wlC;
  }

  const int bb0 = nt*64 + fn0*16 + (lane & 15);
  #pragma unroll
  for (int n = 0; n < 2; n++){
    f32x4 g = n ? acc1 : acc0;
    int b = bb0 + n*16;
    float ig = sigf(g[0]);
    float fg = sigf(g[1]);
    float gg = tanhf(g[2]);
    float og = sigf(g[3]);
    float c2 = fg * c_in[(size_t)b*512 + j0] + ig * gg;
    float h  = og * tanhf(c2);
    c_out[(size_t)b*512 + j0] = c2;
    if (h_f32) h_f32[(size_t)b*512 + j0] = h;
    unsigned short hh = f2bf(h);
    unsigned short hl = f2bf(h - bf2f(hh));
    size_t o0 = pk(b, off0 + j0, KB0);
    out0[o0] = hh; out0[o0 + plane0] = hl;
    if (out1){
      size_t o1 = pk(b, off1 + j0, KB1);
      out1[o1] = hh; out1[o1 + plane1] = hl;
    }
  }
}

// ---------------- z GEMM: 8 waves, K split 2 kb/wave, LDS reduction ----------------
__global__ __launch_bounds__(512) void zgemm8(
    const unsigned short* __restrict__ Wzh, const unsigned short* __restrict__ Wzl,
    const unsigned short* __restrict__ az, int planeZ,
    const float* __restrict__ mu_b, const float* __restrict__ sig_b,
    const float* __restrict__ eps_t,
    unsigned short* __restrict__ actD, int planeD)
{
  __shared__ float zred[8*64*8];
  const int tid = threadIdx.x, lane = tid & 63, w = tid >> 6;
  const int fmb = blockIdx.x & 7, cg = blockIdx.x >> 3;
  const char* azh = (const char*)az + (size_t)cg*16384 + (size_t)lane*16;
  const char* azl = (const char*)(az + planeZ) + (size_t)cg*16384 + (size_t)lane*16;
  const int kb0 = w*2;

  bf16x8 a0h = *(const bf16x8*)(azh + (size_t)kb0*1024);
  bf16x8 a0l = *(const bf16x8*)(azl + (size_t)kb0*1024);
  bf16x8 a1h = *(const bf16x8*)(azh + (size_t)(kb0+1)*1024);
  bf16x8 a1l = *(const bf16x8*)(azl + (size_t)(kb0+1)*1024);

  const bf16x8* wmh = (const bf16x8*)Wzh + (size_t)(fmb    *16)*64 + lane;
  const bf16x8* wml = (const bf16x8*)Wzl + (size_t)(fmb    *16)*64 + lane;
  const bf16x8* wsh = (const bf16x8*)Wzh + (size_t)((fmb+8)*16)*64 + lane;
  const bf16x8* wsl = (const bf16x8*)Wzl + (size_t)((fmb+8)*16)*64 + lane;
  bf16x8 m0h = wmh[kb0*64],     m0l = wml[kb0*64];
  bf16x8 s0h = wsh[kb0*64],     s0l = wsl[kb0*64];
  bf16x8 m1h = wmh[(kb0+1)*64], m1l = wml[(kb0+1)*64];
  bf16x8 s1h = wsh[(kb0+1)*64], s1l = wsl[(kb0+1)*64];

  f32x4 am = {0.f,0.f,0.f,0.f}, as = {0.f,0.f,0.f,0.f};
  am = MFMA(m0h,a0h,am); am = MFMA(m0l,a0h,am); am = MFMA(m0h,a0l,am);
  as = MFMA(s0h,a0h,as); as = MFMA(s0l,a0h,as); as = MFMA(s0h,a0l,as);
  am = MFMA(m1h,a1h,am); am = MFMA(m1l,a1h,am); am = MFMA(m1h,a1l,am);
  as = MFMA(s1h,a1h,as); as = MFMA(s1l,a1h,as); as = MFMA(s1h,a1l,as);

  *(f32x4*)&zred[(size_t)(w*64+lane)*8]     = am;
  *(f32x4*)&zred[(size_t)(w*64+lane)*8 + 4] = as;
  __syncthreads();

  if (w == 0){
    const int r0 = fmb*16 + (lane >> 4)*4;
    float4 bm = *(const float4*)&mu_b[r0];
    float4 bs = *(const float4*)&sig_b[r0];
    f32x4 AM = {bm.x,bm.y,bm.z,bm.w};
    f32x4 AS = {bs.x,bs.y,bs.z,bs.w};
    #pragma unroll
    for (int v = 0; v < 8; v++){
      AM += *(f32x4*)&zred[(size_t)(v*64+lane)*8];
      AS += *(f32x4*)&zred[(size_t)(v*64+lane)*8 + 4];
    }
    const int b = cg*16 + (lane & 15);
    float4 ev = *(const float4*)&eps_t[(size_t)b*128 + r0];
    float e[4] = {ev.x, ev.y, ev.z, ev.w};
    union { unsigned short s[4]; uint2 u; } zh, zl;
    #pragma unroll
    for (int i = 0; i < 4; i++){
      float z = AM[i] + e[i]*__expf(AS[i]);
      unsigned short hi = f2bf(z);
      zh.s[i] = hi;
      zl.s[i] = f2bf(z - bf2f(hi));
    }
    size_t o = pk(b, r0, 20);
    *(uint2*)(actD + o) = zh.u;
    *(uint2*)(actD + planeD + o) = zl.u;
  }
}

// ---------------- fused write(t) + glimpse(t+1) ----------------
__device__ void attn_window(const float* __restrict__ h,
                            const float* __restrict__ attn_W,
                            const float* __restrict__ attn_b,
                            float* Fx, float* Fy, float* pl)
{
  int tid = threadIdx.x;
  int lane = tid & 63, wid = tid >> 6;
  for (int q = wid; q < 5; q += 4){
    float s = 0.f;
    for (int k = lane; k < 512; k += 64) s += h[k]*attn_W[q*512 + k];
    for (int m = 32; m; m >>= 1) s += __shfl_xor(s, m);
    if (lane == 0) pl[q] = s + attn_b[q];
  }
  __syncthreads();
  float gx    = 32.5f*(pl[0] + 1.f);
  float gy    = 32.5f*(pl[1] + 1.f);
  float s2    = __expf(pl[2]);
  float delta = 9.f*__expf(pl[3]);
  float inv2  = 1.f/(2.f*s2);
  int n = tid >> 5, a = tid & 31;
  float mux = gx + ((float)n - 4.5f)*delta;
  float muy = gy + ((float)n - 4.5f)*delta;
  float dx0 = (float)a      - mux, dx1 = (float)(a+32) - mux;
  float dy0 = (float)a      - muy, dy1 = (float)(a+32) - muy;
  float e0 = __expf(-dx0*dx0*inv2), e1 = __expf(-dx1*dx1*inv2);
  float f0 = __expf(-dy0*dy0*inv2), f1 = __expf(-dy1*dy1*inv2);
  float sx = e0 + e1, sy = f0 + f1;
  for (int m = 16; m; m >>= 1){ sx += __shfl_xor(sx, m); sy += __shfl_xor(sy, m); }
  float rx = 1.f/(sx + EPSF), ry = 1.f/(sy + EPSF);
  Fx[n*LDF + a]      = e0*rx;  Fx[n*LDF + a + 32] = e1*rx;
  Fy[n*LDF + a]      = f0*ry;  Fy[n*LDF + a + 32] = f1*ry;
  __syncthreads();
}

__global__ __launch_bounds__(256) void wg_kernel(
    const float* __restrict__ h_dec,
    const float* __restrict__ WwT, const float* __restrict__ write_b,
    const float* __restrict__ attn_W, const float* __restrict__ attn_b,
    const float* __restrict__ canvas_prev, float* __restrict__ canvas_out,
    const float* __restrict__ x,
    unsigned short* __restrict__ rout, int planeE)
{
  __shared__ float hs[512];
  __shared__ float Fx[8*LDF], Fy[8*LDF], pl[8];
  __shared__ float cs[64*LDF];
  __shared__ float img_s[64*LDF];
  __shared__ float P[2][8*LDF];
  __shared__ float ps[4][64], w_s[64];
  __shared__ float tmp[64*8];
  const int b = blockIdx.x, tid = threadIdx.x;

  for (int i = tid; i < 128; i += 256)
    ((float4*)hs)[i] = ((const float4*)(h_dec + (size_t)b*512))[i];
  if (rout){
    const float4* x4 = (const float4*)(x + (size_t)b*4096);
    for (int i = tid; i < 1024; i += 256){
      int row = i >> 4, cb = (i & 15)*4;
      *(float4*)&img_s[row*LDF + cb] = x4[i];
    }
  }
  __syncthreads();
  attn_window(hs, attn_W, attn_b, Fx, Fy, pl);
  float gamma = __expf(pl[4]);

  if (canvas_out){
    {
      int j = tid & 63, part = tid >> 6;
      float s = 0.f;
      int kb = part*128;
      for (int k = 0; k < 128; k++) s += hs[kb + k] * WwT[(kb + k)*64 + j];
      ps[part][j] = s;
    }
    __syncthreads();
    if (tid < 64)
      w_s[tid] = write_b[tid] + ps[0][tid] + ps[1][tid] + ps[2][tid] + ps[3][tid];
    __syncthreads();
    float inv_g = __expf(-pl[4]);
    #pragma unroll
    for (int e = 0; e < 2; e++){
      int gi = e*256 + tid;
      int m = gi & 7, hh = gi >> 3;
      float s = 0.f;
      #pragma unroll
      for (int nn = 0; nn < 8; nn++) s += Fy[nn*LDF + hh] * w_s[nn*8 + m];
      tmp[hh*8 + m] = s;
    }
    __syncthreads();
    for (int e = 0; e < 16; e++){
      int idx = e*256 + tid;
      int hh = idx >> 6, a = idx & 63;
      float s = 0.f;
      #pragma unroll
      for (int m = 0; m < 8; m++) s += tmp[hh*8 + m] * Fx[m*LDF + a];
      float prev = canvas_prev ? canvas_prev[(size_t)b*4096 + idx] : 0.f;
      float cv = prev + s*inv_g;
      canvas_out[(size_t)b*4096 + idx] = cv;
      cs[hh*LDF + a] = cv;
    }
  } else {
    for (int e = 0; e < 16; e++){
      int idx = e*256 + tid;
      cs[(idx >> 6)*LDF + (idx & 63)] = 0.f;
    }
  }
  if (!rout) return;
  __syncthreads();
  for (int e = 0; e < 16; e++){
    int idx = e*256 + tid;
    int hh = idx >> 6, a = idx & 63;
    cs[hh*LDF + a] = sigf(cs[hh*LDF + a]);
  }
  __syncthreads();
  #pragma unroll
  for (int e = 0; e < 4; e++){
    int gi = e*256 + tid;
    int d = gi >> 9, rem = gi & 511;
    int m = rem & 7, hh = rem >> 3;
    const float* S = d ? cs : img_s;
    float s = 0.f;
    #pragma unroll
    for (int w4 = 0; w4 < 64; w4 += 4){
      float4 iv = *(const float4*)&S[hh*LDF + w4];
      float4 fv = *(const float4*)&Fx[m*LDF + w4];
      s += iv.x*fv.x + iv.y*fv.y + iv.z*fv.z + iv.w*fv.w;
    }
    P[d][m*LDF + hh] = s;
  }
  __syncthreads();
  if (tid < 128){
    int d = tid >> 6, l = tid & 63;
    int n = l >> 3, m = l & 7;
    float s = 0.f;
    #pragma unroll
    for (int h4 = 0; h4 < 64; h4 += 4){
      float4 fv = *(const float4*)&Fy[n*LDF + h4];
      float4 pv = *(const float4*)&P[d][m*LDF + h4];
      s += fv.x*pv.x + fv.y*pv.y + fv.z*pv.z + fv.w*pv.w;
    }
    tmp[d*64 + l] = s;
  }
  __syncthreads();
  if (tid < 64){
    float g1 = tmp[tid]*gamma;
    float g2 = (tmp[tid] - tmp[64 + tid])*gamma;
    unsigned short h1 = f2bf(g1), l1 = f2bf(g1 - bf2f(h1));
    unsigned short h2 = f2bf(g2), l2 = f2bf(g2 - bf2f(h2));
    size_t o1 = pk(b, tid, 36);
    size_t o2 = pk(b, 64 + tid, 36);
    rout[o1] = h1; rout[o1 + planeE] = l1;
    rout[o2] = h2; rout[o2 + planeE] = l2;
  }
}

// ---------------- host launcher ----------------
extern "C" void kernel_launch(void* const* d_in, const int* in_sizes, int n_in,
                              void* d_out, int out_size, void* d_ws, size_t ws_size,
                              hipStream_t stream)
{
  (void)in_sizes; (void)n_in; (void)out_size; (void)ws_size;
  const float* x       = (const float*)d_in[0];
  const float* eps     = (const float*)d_in[1];
  const float* encWih  = (const float*)d_in[2];
  const float* encWhh  = (const float*)d_in[3];
  const float* enc_b   = (const float*)d_in[4];
  const float* muW     = (const float*)d_in[5];
  const float* mu_b    = (const float*)d_in[6];
  const float* sigW    = (const float*)d_in[7];
  const float* sig_b   = (const float*)d_in[8];
  const float* decWih  = (const float*)d_in[9];
  const float* decWhh  = (const float*)d_in[10];
  const float* dec_b   = (const float*)d_in[11];
  const float* writeW  = (const float*)d_in[12];
  const float* write_b = (const float*)d_in[13];
  const float* attnW   = (const float*)d_in[14];
  const float* attn_b  = (const float*)d_in[15];
  float* out = (float*)d_out;

  char* p = (char*)d_ws;
  auto alloc = [&](size_t bytes){ char* r = p; p += (bytes + 255) & ~(size_t)255; return r; };

  const int KE = 1152, KD = 640;
  const int PE = 512*KE, PD = 512*KD, PZ = 512*512;
  const int T8E = 128*36*64, T8D = 128*20*64;

  unsigned short* WpEh = (unsigned short*)alloc((size_t)T8E*16);
  unsigned short* WpEl = (unsigned short*)alloc((size_t)T8E*16);
  unsigned short* WpDh = (unsigned short*)alloc((size_t)T8D*16);
  unsigned short* WpDl = (unsigned short*)alloc((size_t)T8D*16);
  unsigned short* Wzh  = (unsigned short*)alloc(16384*16);
  unsigned short* Wzl  = (unsigned short*)alloc(16384*16);
  float* bE  = (float*)alloc(2048*4);
  float* bD  = (float*)alloc(2048*4);
  float* WwT = (float*)alloc(512*64*4);
  // zero-init region
  char* z0 = p;
  unsigned short* actE0 = (unsigned short*)alloc((size_t)2*PE*2);
  unsigned short* actD0 = (unsigned short*)alloc((size_t)2*PD*2);
  float* hDf = (float*)alloc(512*512*4);
  float* cE0 = (float*)alloc(512*512*4);
  float* cD0 = (float*)alloc(512*512*4);
  size_t zbytes = (size_t)(p - z0);
  unsigned short* actE1 = (unsigned short*)alloc((size_t)2*PE*2);
  unsigned short* actD1 = (unsigned short*)alloc((size_t)2*PD*2);
  unsigned short* AZ    = (unsigned short*)alloc((size_t)2*PZ*2);
  float* cE1 = (float*)alloc(512*512*4);
  float* cD1 = (float*)alloc(512*512*4);

  unsigned short* actE[2] = { actE0, actE1 };
  unsigned short* actD[2] = { actD0, actD1 };
  float* cEf[2] = { cE0, cE1 };
  float* cDf[2] = { cD0, cD1 };

  int tot;
  tot = T8E;   pack_w_mfma<<<(tot+255)/256,256,0,stream>>>(encWih, encWhh, 640, KE, WpEh, WpEl, tot);
  tot = T8D;   pack_w_mfma<<<(tot+255)/256,256,0,stream>>>(decWih, decWhh, 128, KD, WpDh, WpDl, tot);
  tot = 2048+2048+32768+16384;
  init_misc<<<(tot+255)/256,256,0,stream>>>(enc_b, dec_b, writeW, muW, sigW,
                                            bE, bD, WwT, Wzh, Wzl);
  tot = (int)(zbytes/4); zero_f<<<(tot+255)/256,256,0,stream>>>((float*)z0, tot);

  // pre-loop glimpse (t=0): zero canvas, zero h_dec
  wg_kernel<<<512,256,0,stream>>>(hDf, WwT, write_b, attnW, attn_b,
                                  nullptr, nullptr, x, actE[0], PE);

  for (int t = 0; t < 16; t++){
    int cur = t & 1, nxt = cur ^ 1;

    mfma_gemm_lstm<36><<<256,512,0,stream>>>(
        (const bf16x8*)WpEh, (const bf16x8*)WpEl, actE[cur], PE,
        (const float4*)bE, cEf[cur], nullptr, cEf[nxt],
        AZ, 16, 0, PZ,
        actE[nxt], 36, 640, PE);

    zgemm8<<<256,512,0,stream>>>(
        Wzh, Wzl, AZ, PZ, mu_b, sig_b,
        eps + (size_t)t*65536, actD[cur], PD);

    mfma_gemm_lstm<20><<<256,512,0,stream>>>(
        (const bf16x8*)WpDh, (const bf16x8*)WpDl, actD[cur], PD,
        (const float4*)bD, cDf[cur], hDf, cDf[nxt],
        actE[nxt], 36, 128, PE,
        actD[nxt], 20, 128, PD);

    wg_kernel<<<512,256,0,stream>>>(hDf, WwT, write_b, attnW, attn_b,
                                    t ? (out + (size_t)(t-1)*2097152) : nullptr,
                                    out + (size_t)t*2097152, x,
                                    (t < 15) ? actE[nxt] : nullptr, PE);
  }
}